// Round 1
// baseline (2163.608 us; speedup 1.0000x reference)
//
#include <hip/hip_runtime.h>
#include <hip/hip_bf16.h>

#define NNODES 100000

// ---------------- CSR build ----------------
__global__ void hist_kernel(const int* __restrict__ dst, int E, int* __restrict__ deg) {
    int e = blockIdx.x * blockDim.x + threadIdx.x;
    if (e < E) atomicAdd(&deg[dst[e]], 1);
}

__global__ __launch_bounds__(1024) void scan_kernel(const int* __restrict__ deg,
                                                    int* __restrict__ rowptr, int n) {
    __shared__ int part[1024];
    int t = threadIdx.x;
    int chunk = (n + 1023) >> 10;
    int start = t * chunk;
    int end = min(start + chunk, n);
    int s = 0;
    for (int i = start; i < end; ++i) s += deg[i];
    part[t] = s;
    __syncthreads();
    for (int off = 1; off < 1024; off <<= 1) {
        int v = (t >= off) ? part[t - off] : 0;
        __syncthreads();
        part[t] += v;
        __syncthreads();
    }
    int run = (t == 0) ? 0 : part[t - 1];
    for (int i = start; i < end; ++i) { rowptr[i] = run; run += deg[i]; }
    if (t == 1023) rowptr[n] = run;
}

__global__ void scatter_kernel(const int* __restrict__ src, const int* __restrict__ dst, int E,
                               const int* __restrict__ rowptr, int* __restrict__ cursor,
                               int* __restrict__ csr) {
    int e = blockIdx.x * blockDim.x + threadIdx.x;
    if (e < E) {
        int d = dst[e];
        int pos = rowptr[d] + atomicAdd(&cursor[d], 1);
        csr[pos] = src[e];
    }
}

// ---------------- GEMM: C[M,N] = A[M,K] @ B[K,N] + bias[N] ----------------
#define BM 128
#define BN 128
#define BK 8

__global__ __launch_bounds__(256) void gemm_bias(const float* __restrict__ A,
                                                 const float* __restrict__ B,
                                                 const float* __restrict__ bias,
                                                 float* __restrict__ C,
                                                 int M, int N, int K) {
    __shared__ float As[BK][BM];   // transposed A tile: As[k][m]
    __shared__ float Bs[BK][BN];
    int t = threadIdx.x;
    int row0 = blockIdx.x * BM;
    int col0 = blockIdx.y * BN;
    int ty = t >> 4, tx = t & 15;          // 16x16 thread grid, 8x8 per thread
    int ar = t >> 1, ac4 = (t & 1) * 4;    // A load: 4 consecutive k per thread
    int br = t >> 5, bc = (t & 31) * 4;    // B load: float4-worth per thread

    float acc[8][8];
#pragma unroll
    for (int i = 0; i < 8; ++i)
#pragma unroll
        for (int j = 0; j < 8; ++j) acc[i][j] = 0.f;

    for (int k0 = 0; k0 < K; k0 += BK) {
        // load A tile (transposed into LDS), guarded
        float a0 = 0.f, a1 = 0.f, a2 = 0.f, a3 = 0.f;
        int grow = row0 + ar;
        if (grow < M) {
            const float* Ap = A + (size_t)grow * K + k0 + ac4;
            int rem = K - (k0 + ac4);
            if (rem > 0) a0 = Ap[0];
            if (rem > 1) a1 = Ap[1];
            if (rem > 2) a2 = Ap[2];
            if (rem > 3) a3 = Ap[3];
        }
        As[ac4 + 0][ar] = a0;
        As[ac4 + 1][ar] = a1;
        As[ac4 + 2][ar] = a2;
        As[ac4 + 3][ar] = a3;
        // load B tile, guarded
        float b0 = 0.f, b1 = 0.f, b2 = 0.f, b3 = 0.f;
        int gk = k0 + br;
        if (gk < K) {
            int gc = col0 + bc;
            const float* Bp = B + (size_t)gk * N + gc;
            if (gc + 0 < N) b0 = Bp[0];
            if (gc + 1 < N) b1 = Bp[1];
            if (gc + 2 < N) b2 = Bp[2];
            if (gc + 3 < N) b3 = Bp[3];
        }
        Bs[br][bc + 0] = b0;
        Bs[br][bc + 1] = b1;
        Bs[br][bc + 2] = b2;
        Bs[br][bc + 3] = b3;
        __syncthreads();
#pragma unroll
        for (int kk = 0; kk < BK; ++kk) {
            float av[8], bv[8];
#pragma unroll
            for (int i = 0; i < 8; ++i) av[i] = As[kk][ty * 8 + i];
#pragma unroll
            for (int j = 0; j < 8; ++j) bv[j] = Bs[kk][tx * 8 + j];
#pragma unroll
            for (int i = 0; i < 8; ++i)
#pragma unroll
                for (int j = 0; j < 8; ++j) acc[i][j] += av[i] * bv[j];
        }
        __syncthreads();
    }
#pragma unroll
    for (int i = 0; i < 8; ++i) {
        int r = row0 + ty * 8 + i;
        if (r >= M) continue;
#pragma unroll
        for (int j = 0; j < 8; ++j) {
            int c = col0 + tx * 8 + j;
            if (c < N) C[(size_t)r * N + c] = acc[i][j] + bias[c];
        }
    }
}

// ---------------- GATv2 aggregation (one block per dst node) ----------------
// blockDim.x = HC (= H*CDIM); thread t <-> (h = t/CDIM, c = t%CDIM)
template <int CDIM>
__global__ void gat_aggregate(const float* __restrict__ xl, const float* __restrict__ xr,
                              const float* __restrict__ resid, const float* __restrict__ att,
                              const float* __restrict__ bias, const int* __restrict__ rowptr,
                              const int* __restrict__ csr, float* __restrict__ hout, int HC) {
    int n = blockIdx.x;
    int t = threadIdx.x;
    float xr_t = xr[(size_t)n * HC + t];
    float att_t = att[t];   // att[h*CDIM + c] == att[t]
    int s0 = rowptr[n], s1 = rowptr[n + 1];
    float m = -__builtin_inff();
    float ssum = 0.f, acc = 0.f;
    for (int i = s0; i < s1; ++i) {
        int src = csr[i];
        float xv = xl[(size_t)src * HC + t];
        float v = xv + xr_t;
        float lr = v > 0.f ? v : 0.2f * v;
        float prod = lr * att_t;
#pragma unroll
        for (int o = CDIM >> 1; o > 0; o >>= 1) prod += __shfl_xor(prod, o);
        float e = prod;                 // per-head score, replicated across CDIM lanes
        float mn = fmaxf(m, e);
        float sc = __expf(m - mn);
        float p = __expf(e - mn);
        ssum = ssum * sc + p;
        acc = acc * sc + p * xv;
        m = mn;
    }
    float g = (s1 > s0) ? acc / (ssum + 1e-16f) : 0.f;
    float y = g + bias[t] + resid[(size_t)n * HC + t];
    float out = 0.5f * y * (1.f + erff(y * 0.70710678118654752f));
    hout[(size_t)n * HC + t] = out;
}

// ---------------- final linear 64 -> 32 ----------------
__global__ __launch_bounds__(256) void final_linear(const float* __restrict__ h,
                                                    const float* __restrict__ W,
                                                    const float* __restrict__ b,
                                                    float* __restrict__ out, int M) {
    __shared__ float Ws[64 * 32];
    __shared__ float bs[32];
    __shared__ float hs[8][64];
    int t = threadIdx.x;
    for (int i = t; i < 64 * 32; i += 256) Ws[i] = W[i];
    if (t < 32) bs[t] = b[t];
    int r0 = blockIdx.x * 8;
    for (int i = t; i < 8 * 64; i += 256) {
        int r = i >> 6, c = i & 63;
        hs[r][c] = (r0 + r < M) ? h[(size_t)(r0 + r) * 64 + c] : 0.f;
    }
    __syncthreads();
    int lr = t >> 5;         // 0..7
    int col = t & 31;        // 0..31
    int row = r0 + lr;
    if (row >= M) return;
    float acc = bs[col];
#pragma unroll 8
    for (int k = 0; k < 64; ++k) acc += hs[lr][k] * Ws[k * 32 + col];
    out[(size_t)row * 32 + col] = acc;
}

extern "C" void kernel_launch(void* const* d_in, const int* in_sizes, int n_in,
                              void* d_out, int out_size, void* d_ws, size_t ws_size,
                              hipStream_t stream) {
    const float* x = (const float*)d_in[0];
    const int* ei = (const int*)d_in[1];
    const int E = in_sizes[1] / 2;
    const int* srcp = ei;
    const int* dstp = ei + E;

    const float* Wl[4]  = {(const float*)d_in[2],  (const float*)d_in[8],  (const float*)d_in[14], (const float*)d_in[20]};
    const float* bl[4]  = {(const float*)d_in[3],  (const float*)d_in[9],  (const float*)d_in[15], (const float*)d_in[21]};
    const float* Wr[4]  = {(const float*)d_in[4],  (const float*)d_in[10], (const float*)d_in[16], (const float*)d_in[22]};
    const float* br[4]  = {(const float*)d_in[5],  (const float*)d_in[11], (const float*)d_in[17], (const float*)d_in[23]};
    const float* att[4] = {(const float*)d_in[6],  (const float*)d_in[12], (const float*)d_in[18], (const float*)d_in[24]};
    const float* bia[4] = {(const float*)d_in[7],  (const float*)d_in[13], (const float*)d_in[19], (const float*)d_in[25]};
    const float* proj1W = (const float*)d_in[26];
    const float* proj1b = (const float*)d_in[27];
    const float* proj4W = (const float*)d_in[28];
    const float* proj4b = (const float*)d_in[29];
    const float* linW   = (const float*)d_in[30];
    const float* linb   = (const float*)d_in[31];

    const int M = NNODES;
    char* ws = (char*)d_ws;
    float* xl  = (float*)ws; ws += (size_t)M * 128 * sizeof(float);
    float* xr  = (float*)ws; ws += (size_t)M * 128 * sizeof(float);
    float* res = (float*)ws; ws += (size_t)M * 128 * sizeof(float);
    float* h   = (float*)ws; ws += (size_t)M * 128 * sizeof(float);
    int* deg    = (int*)ws; ws += (size_t)M * sizeof(int);
    int* cursor = (int*)ws; ws += (size_t)M * sizeof(int);
    int* rowptr = (int*)ws; ws += (size_t)(M + 1) * sizeof(int);
    int* csr    = (int*)ws; ws += (size_t)E * sizeof(int);

    // ---- CSR build (deg and cursor are contiguous -> one memset) ----
    hipMemsetAsync(deg, 0, 2 * (size_t)M * sizeof(int), stream);
    hist_kernel<<<(E + 255) / 256, 256, 0, stream>>>(dstp, E, deg);
    scan_kernel<<<1, 1024, 0, stream>>>(deg, rowptr, M);
    scatter_kernel<<<(E + 255) / 256, 256, 0, stream>>>(srcp, dstp, E, rowptr, cursor, csr);

    dim3 gemm_grid((M + BM - 1) / BM, 1);   // N <= 128 for all GEMMs here
    // ---- layer 1 (fin=193, HC=128, C=16), residual = x @ proj1 ----
    gemm_bias<<<gemm_grid, 256, 0, stream>>>(x, Wl[0], bl[0], xl, M, 128, 193);
    gemm_bias<<<gemm_grid, 256, 0, stream>>>(x, Wr[0], br[0], xr, M, 128, 193);
    gemm_bias<<<gemm_grid, 256, 0, stream>>>(x, proj1W, proj1b, res, M, 128, 193);
    gat_aggregate<16><<<M, 128, 0, stream>>>(xl, xr, res, att[0], bia[0], rowptr, csr, h, 128);
    // ---- layer 2 (fin=128, HC=128), residual = h ----
    gemm_bias<<<gemm_grid, 256, 0, stream>>>(h, Wl[1], bl[1], xl, M, 128, 128);
    gemm_bias<<<gemm_grid, 256, 0, stream>>>(h, Wr[1], br[1], xr, M, 128, 128);
    gat_aggregate<16><<<M, 128, 0, stream>>>(xl, xr, h, att[1], bia[1], rowptr, csr, h, 128);
    // ---- layer 3 ----
    gemm_bias<<<gemm_grid, 256, 0, stream>>>(h, Wl[2], bl[2], xl, M, 128, 128);
    gemm_bias<<<gemm_grid, 256, 0, stream>>>(h, Wr[2], br[2], xr, M, 128, 128);
    gat_aggregate<16><<<M, 128, 0, stream>>>(xl, xr, h, att[2], bia[2], rowptr, csr, h, 128);
    // ---- layer 4 (fin=128, HC=64, C=8), residual = h @ proj4 ----
    gemm_bias<<<gemm_grid, 256, 0, stream>>>(h, Wl[3], bl[3], xl, M, 64, 128);
    gemm_bias<<<gemm_grid, 256, 0, stream>>>(h, Wr[3], br[3], xr, M, 64, 128);
    gemm_bias<<<gemm_grid, 256, 0, stream>>>(h, proj4W, proj4b, res, M, 64, 128);
    gat_aggregate<8><<<M, 64, 0, stream>>>(xl, xr, res, att[3], bia[3], rowptr, csr, h, 64);
    // ---- final linear 64 -> 32 ----
    final_linear<<<(M + 7) / 8, 256, 0, stream>>>(h, linW, linb, (float*)d_out, M);
}

// Round 2
// 1918.166 us; speedup vs baseline: 1.1280x; 1.1280x over previous
//
#include <hip/hip_runtime.h>
#include <hip/hip_bf16.h>

#define NNODES 100000

// ---------------- CSR build ----------------
__global__ void hist_kernel(const int* __restrict__ dst, int E, int* __restrict__ deg) {
    int e = blockIdx.x * blockDim.x + threadIdx.x;
    if (e < E) atomicAdd(&deg[dst[e]], 1);
}

__global__ __launch_bounds__(1024) void scan_kernel(const int* __restrict__ deg,
                                                    int* __restrict__ rowptr, int n) {
    __shared__ int part[1024];
    int t = threadIdx.x;
    int chunk = (n + 1023) >> 10;
    int start = t * chunk;
    int end = min(start + chunk, n);
    int s = 0;
    for (int i = start; i < end; ++i) s += deg[i];
    part[t] = s;
    __syncthreads();
    for (int off = 1; off < 1024; off <<= 1) {
        int v = (t >= off) ? part[t - off] : 0;
        __syncthreads();
        part[t] += v;
        __syncthreads();
    }
    int run = (t == 0) ? 0 : part[t - 1];
    for (int i = start; i < end; ++i) { rowptr[i] = run; run += deg[i]; }
    if (t == 1023) rowptr[n] = run;
}

__global__ void scatter_kernel(const int* __restrict__ src, const int* __restrict__ dst, int E,
                               const int* __restrict__ rowptr, int* __restrict__ cursor,
                               int* __restrict__ csr) {
    int e = blockIdx.x * blockDim.x + threadIdx.x;
    if (e < E) {
        int d = dst[e];
        int pos = rowptr[d] + atomicAdd(&cursor[d], 1);
        csr[pos] = src[e];
    }
}

// ---------------- GEMM: C[:, col0:col0+BN] = A[M,K] @ B[K,BN] + bias ----------------
// BM=128, BK=16, 256 threads, per-thread 8 x TN. B is exactly BN wide.
template <int TN>   // TN=8 -> BN=128, TN=4 -> BN=64
__global__ __launch_bounds__(256) void gemm_bias_f32(const float* __restrict__ A,
                                                     const float* __restrict__ B,
                                                     const float* __restrict__ bias,
                                                     float* __restrict__ C,
                                                     int M, int K, int Cstride, int col0) {
    constexpr int BN = TN * 16;
    __shared__ float As[16][128];
    __shared__ float Bs[16][BN];
    int t = threadIdx.x;
    int row0 = blockIdx.x * 128;
    int ty = t >> 4, tx = t & 15;

    float acc[8][TN];
#pragma unroll
    for (int i = 0; i < 8; ++i)
#pragma unroll
        for (int j = 0; j < TN; ++j) acc[i][j] = 0.f;

    int arow = t >> 1;
    int akg = (t & 1) * 8;
    const float* Arow = A + (size_t)(row0 + arow) * K;
    bool aval = (row0 + arow) < M;
    int brow = t >> 4;
    int bcol = (t & 15) * TN;

    for (int k0 = 0; k0 < K; k0 += 16) {
        // A tile -> transposed LDS (scalar loads: tolerant of any row stride/K)
#pragma unroll
        for (int j = 0; j < 8; ++j) {
            int k = k0 + akg + j;
            As[akg + j][arow] = (aval && k < K) ? Arow[k] : 0.f;
        }
        // B tile (float4 loads; B buffers are BN wide, 16B-aligned rows)
        if (TN == 8) {
            float4 b0 = make_float4(0.f, 0.f, 0.f, 0.f);
            float4 b1 = make_float4(0.f, 0.f, 0.f, 0.f);
            if (k0 + brow < K) {
                const float* Bp = B + (size_t)(k0 + brow) * BN + bcol;
                b0 = *(const float4*)(Bp);
                b1 = *(const float4*)(Bp + 4);
            }
            *(float4*)&Bs[brow][bcol] = b0;
            *(float4*)&Bs[brow][bcol + 4] = b1;
        } else {
            float4 b0 = make_float4(0.f, 0.f, 0.f, 0.f);
            if (k0 + brow < K) b0 = *(const float4*)(B + (size_t)(k0 + brow) * BN + bcol);
            *(float4*)&Bs[brow][bcol] = b0;
        }
        __syncthreads();
#pragma unroll
        for (int kk = 0; kk < 16; ++kk) {
            float av[8], bv[TN];
#pragma unroll
            for (int i = 0; i < 8; ++i) av[i] = As[kk][ty * 8 + i];
#pragma unroll
            for (int j = 0; j < TN; ++j) bv[j] = Bs[kk][tx * TN + j];
#pragma unroll
            for (int i = 0; i < 8; ++i)
#pragma unroll
                for (int j = 0; j < TN; ++j) acc[i][j] = fmaf(av[i], bv[j], acc[i][j]);
        }
        __syncthreads();
    }
#pragma unroll
    for (int i = 0; i < 8; ++i) {
        int r = row0 + ty * 8 + i;
        if (r >= M) continue;
#pragma unroll
        for (int j = 0; j < TN; ++j) {
            int c = tx * TN + j;
            C[(size_t)r * Cstride + col0 + c] = acc[i][j] + bias[c];
        }
    }
}

// ---------------- GATv2 aggregation: one wave per node ----------------
// CPL components per lane; HC = 64*CPL. C (head dim) = 16 (CPL=2) or 8 (CPL=1);
// either way one head spans 8 lanes -> shfl_xor 1,2,4 reduce.
template <int CPL>
__global__ __launch_bounds__(256) void gat_agg(const float* __restrict__ xcat, int xstride,
                                               int xr_off,
                                               const float* __restrict__ res, int rstride, int roff,
                                               const float* __restrict__ att,
                                               const float* __restrict__ bias,
                                               const int* __restrict__ rowptr,
                                               const int* __restrict__ csr,
                                               float* __restrict__ hout, int hstride, int M) {
    int n = blockIdx.x * 4 + (threadIdx.x >> 6);
    if (n >= M) return;
    int t = threadIdx.x & 63;

    float xr0, xr1 = 0.f, at0, at1 = 0.f;
    if (CPL == 2) {
        float2 xr2 = *(const float2*)(xcat + (size_t)n * xstride + xr_off + 2 * t);
        float2 at2 = *(const float2*)(att + 2 * t);
        xr0 = xr2.x; xr1 = xr2.y; at0 = at2.x; at1 = at2.y;
    } else {
        xr0 = xcat[(size_t)n * xstride + xr_off + t];
        at0 = att[t];
    }

    int s0 = rowptr[n], s1 = rowptr[n + 1];
    float ssum = 0.f, a0 = 0.f, a1 = 0.f;
    if (s1 > s0) {
        // prefetch first row
        int sp = csr[s0];
        float c0, c1 = 0.f;
        if (CPL == 2) {
            float2 v = *(const float2*)(xcat + (size_t)sp * xstride + 2 * t);
            c0 = v.x; c1 = v.y;
        } else {
            c0 = xcat[(size_t)sp * xstride + t];
        }
        for (int i = s0; i < s1; ++i) {
            float x0 = c0, x1 = c1;
            if (i + 1 < s1) {   // prefetch next row while computing current
                int spn = csr[i + 1];
                if (CPL == 2) {
                    float2 v = *(const float2*)(xcat + (size_t)spn * xstride + 2 * t);
                    c0 = v.x; c1 = v.y;
                } else {
                    c0 = xcat[(size_t)spn * xstride + t];
                }
            }
            float v0 = x0 + xr0, v1 = x1 + xr1;
            float l0 = v0 > 0.f ? v0 : 0.2f * v0;
            float l1 = v1 > 0.f ? v1 : 0.2f * v1;
            // scores bounded (|e| ~ <6): exp safe in f32 without max subtraction
            float prod = (CPL == 2) ? fmaf(l1, at1, l0 * at0) : l0 * at0;
            prod += __shfl_xor(prod, 1);
            prod += __shfl_xor(prod, 2);
            prod += __shfl_xor(prod, 4);
            float p = __expf(prod);
            ssum += p;
            a0 = fmaf(p, x0, a0);
            a1 = fmaf(p, x1, a1);
        }
    }
    float inv = 1.f / (ssum + 1e-16f);
    if (CPL == 2) {
        float2 rs = *(const float2*)(res + (size_t)n * rstride + roff + 2 * t);
        float2 bs = *(const float2*)(bias + 2 * t);
        float y0 = fmaf(a0, inv, bs.x + rs.x);
        float y1 = fmaf(a1, inv, bs.y + rs.y);
        float o0 = 0.5f * y0 * (1.f + erff(y0 * 0.70710678118654752f));
        float o1 = 0.5f * y1 * (1.f + erff(y1 * 0.70710678118654752f));
        *(float2*)(hout + (size_t)n * hstride + 2 * t) = make_float2(o0, o1);
    } else {
        float y0 = fmaf(a0, inv, bias[t] + res[(size_t)n * rstride + roff + t]);
        float o0 = 0.5f * y0 * (1.f + erff(y0 * 0.70710678118654752f));
        hout[(size_t)n * hstride + t] = o0;
    }
}

// ---------------- final linear 64 -> 32 ----------------
__global__ __launch_bounds__(256) void final_linear(const float* __restrict__ h,
                                                    const float* __restrict__ W,
                                                    const float* __restrict__ b,
                                                    float* __restrict__ out, int M) {
    __shared__ float Ws[64 * 32];
    __shared__ float bs[32];
    __shared__ float hs[8][64];
    int t = threadIdx.x;
    for (int i = t; i < 64 * 32; i += 256) Ws[i] = W[i];
    if (t < 32) bs[t] = b[t];
    int r0 = blockIdx.x * 8;
    for (int i = t; i < 8 * 64; i += 256) {
        int r = i >> 6, c = i & 63;
        hs[r][c] = (r0 + r < M) ? h[(size_t)(r0 + r) * 64 + c] : 0.f;
    }
    __syncthreads();
    int lr = t >> 5;
    int col = t & 31;
    int row = r0 + lr;
    if (row >= M) return;
    float acc = bs[col];
#pragma unroll 8
    for (int k = 0; k < 64; ++k) acc += hs[lr][k] * Ws[k * 32 + col];
    out[(size_t)row * 32 + col] = acc;
}

extern "C" void kernel_launch(void* const* d_in, const int* in_sizes, int n_in,
                              void* d_out, int out_size, void* d_ws, size_t ws_size,
                              hipStream_t stream) {
    const float* x = (const float*)d_in[0];
    const int* ei = (const int*)d_in[1];
    const int E = in_sizes[1] / 2;
    const int* srcp = ei;
    const int* dstp = ei + E;

    const float* Wl[4]  = {(const float*)d_in[2],  (const float*)d_in[8],  (const float*)d_in[14], (const float*)d_in[20]};
    const float* bl[4]  = {(const float*)d_in[3],  (const float*)d_in[9],  (const float*)d_in[15], (const float*)d_in[21]};
    const float* Wr[4]  = {(const float*)d_in[4],  (const float*)d_in[10], (const float*)d_in[16], (const float*)d_in[22]};
    const float* br[4]  = {(const float*)d_in[5],  (const float*)d_in[11], (const float*)d_in[17], (const float*)d_in[23]};
    const float* att[4] = {(const float*)d_in[6],  (const float*)d_in[12], (const float*)d_in[18], (const float*)d_in[24]};
    const float* bia[4] = {(const float*)d_in[7],  (const float*)d_in[13], (const float*)d_in[19], (const float*)d_in[25]};
    const float* proj1W = (const float*)d_in[26];
    const float* proj1b = (const float*)d_in[27];
    const float* proj4W = (const float*)d_in[28];
    const float* proj4b = (const float*)d_in[29];
    const float* linW   = (const float*)d_in[30];
    const float* linb   = (const float*)d_in[31];

    const int M = NNODES;
    // workspace layout (floats): bufA[M*384] | h[M*128] | ints
    float* bufA = (float*)d_ws;                 // xcat1 [M,384]; later xcat23 [M,256], xcat4 [M,192] + h4
    float* h    = bufA + (size_t)M * 384;       // [M,128]
    int* deg    = (int*)(h + (size_t)M * 128);
    int* cursor = deg + M;
    int* rowptr = cursor + M;
    int* csr    = rowptr + (M + 1);
    float* h4   = bufA + (size_t)M * 192;       // [M,64], disjoint from xcat4 [0, M*192)

    // ---- CSR build ----
    hipMemsetAsync(deg, 0, 2 * (size_t)M * sizeof(int), stream);
    hist_kernel<<<(E + 255) / 256, 256, 0, stream>>>(dstp, E, deg);
    scan_kernel<<<1, 1024, 0, stream>>>(deg, rowptr, M);
    scatter_kernel<<<(E + 255) / 256, 256, 0, stream>>>(srcp, dstp, E, rowptr, cursor, csr);

    dim3 gg((M + 127) / 128, 1);
    dim3 ag((M + 3) / 4, 1);

    // ---- layer 1: fin=193, HC=128; xcat1 = [xl | xr | res], stride 384 ----
    gemm_bias_f32<8><<<gg, 256, 0, stream>>>(x, Wl[0], bl[0], bufA, M, 193, 384, 0);
    gemm_bias_f32<8><<<gg, 256, 0, stream>>>(x, Wr[0], br[0], bufA, M, 193, 384, 128);
    gemm_bias_f32<8><<<gg, 256, 0, stream>>>(x, proj1W, proj1b, bufA, M, 193, 384, 256);
    gat_agg<2><<<ag, 256, 0, stream>>>(bufA, 384, 128, bufA, 384, 256, att[0], bia[0],
                                       rowptr, csr, h, 128, M);
    // ---- layer 2: xcat23 = [xl | xr], stride 256; residual = h (in-place update ok) ----
    gemm_bias_f32<8><<<gg, 256, 0, stream>>>(h, Wl[1], bl[1], bufA, M, 128, 256, 0);
    gemm_bias_f32<8><<<gg, 256, 0, stream>>>(h, Wr[1], br[1], bufA, M, 128, 256, 128);
    gat_agg<2><<<ag, 256, 0, stream>>>(bufA, 256, 128, h, 128, 0, att[1], bia[1],
                                       rowptr, csr, h, 128, M);
    // ---- layer 3 ----
    gemm_bias_f32<8><<<gg, 256, 0, stream>>>(h, Wl[2], bl[2], bufA, M, 128, 256, 0);
    gemm_bias_f32<8><<<gg, 256, 0, stream>>>(h, Wr[2], br[2], bufA, M, 128, 256, 128);
    gat_agg<2><<<ag, 256, 0, stream>>>(bufA, 256, 128, h, 128, 0, att[2], bia[2],
                                       rowptr, csr, h, 128, M);
    // ---- layer 4: HC=64; xcat4 = [xl | xr | res], stride 192 ----
    gemm_bias_f32<4><<<gg, 256, 0, stream>>>(h, Wl[3], bl[3], bufA, M, 128, 192, 0);
    gemm_bias_f32<4><<<gg, 256, 0, stream>>>(h, Wr[3], br[3], bufA, M, 128, 192, 64);
    gemm_bias_f32<4><<<gg, 256, 0, stream>>>(h, proj4W, proj4b, bufA, M, 128, 192, 128);
    gat_agg<1><<<ag, 256, 0, stream>>>(bufA, 192, 64, bufA, 192, 128, att[3], bia[3],
                                       rowptr, csr, h4, 64, M);
    // ---- final linear 64 -> 32 ----
    final_linear<<<(M + 7) / 8, 256, 0, stream>>>(h4, linW, linb, (float*)d_out, M);
}

// Round 3
// 1440.730 us; speedup vs baseline: 1.5017x; 1.3314x over previous
//
#include <hip/hip_runtime.h>
#include <hip/hip_bf16.h>

#define NNODES 100000

typedef short s16x8 __attribute__((ext_vector_type(8)));
typedef float f32x4 __attribute__((ext_vector_type(4)));

__device__ inline ushort f2bf(float f) {   // round-to-nearest-even
    uint u = __float_as_uint(f);
    uint r = u + 0x7fffu + ((u >> 16) & 1u);
    return (ushort)(r >> 16);
}
__device__ inline float bf2f(ushort u) { return __uint_as_float(((uint)u) << 16); }
__device__ inline float bflo(uint u) { return __uint_as_float(u << 16); }
__device__ inline float bfhi(uint u) { return __uint_as_float(u & 0xffff0000u); }

// ---------------- CSR build ----------------
__global__ void hist_kernel(const int* __restrict__ dst, int E, int* __restrict__ deg) {
    int e = blockIdx.x * blockDim.x + threadIdx.x;
    if (e < E) atomicAdd(&deg[dst[e]], 1);
}

__global__ __launch_bounds__(1024) void scan_kernel(const int* __restrict__ deg,
                                                    int* __restrict__ rowptr, int n) {
    __shared__ int part[1024];
    int t = threadIdx.x;
    int chunk = (n + 1023) >> 10;
    int start = t * chunk;
    int end = min(start + chunk, n);
    int s = 0;
    for (int i = start; i < end; ++i) s += deg[i];
    part[t] = s;
    __syncthreads();
    for (int off = 1; off < 1024; off <<= 1) {
        int v = (t >= off) ? part[t - off] : 0;
        __syncthreads();
        part[t] += v;
        __syncthreads();
    }
    int run = (t == 0) ? 0 : part[t - 1];
    for (int i = start; i < end; ++i) { rowptr[i] = run; run += deg[i]; }
    if (t == 1023) rowptr[n] = run;
}

__global__ void scatter_kernel(const int* __restrict__ src, const int* __restrict__ dst, int E,
                               const int* __restrict__ rowptr, int* __restrict__ cursor,
                               int* __restrict__ csr) {
    int e = blockIdx.x * blockDim.x + threadIdx.x;
    if (e < E) {
        int d = dst[e];
        int pos = rowptr[d] + atomicAdd(&cursor[d], 1);
        csr[pos] = src[e];
    }
}

// ---------------- weight conversion: W[K,N] f32 -> Wt[N,Kp] bf16 (transposed, K zero-padded) ----------------
struct WConvDesc { const float* W; ushort* Wt; int K, N, Kp; };
struct WConvArgs { WConvDesc d[10]; };

__global__ void convert_weights(WConvArgs args) {
    WConvDesc dd = args.d[blockIdx.y];
    int total = dd.N * dd.Kp;
    for (int i = blockIdx.x * 256 + threadIdx.x; i < total; i += gridDim.x * 256) {
        int n = i / dd.Kp, k = i - n * dd.Kp;
        float v = (k < dd.K) ? dd.W[(size_t)k * dd.N + n] : 0.f;
        dd.Wt[i] = f2bf(v);
    }
}

// ---------------- MFMA GEMM: C[:, col0:col0+BN] (bf16, strided) = A[M,K] f32 @ Wt^T + bias ----------------
// BM=128, BK=32, 256 threads (4 waves). Wt is [BN][Kp] bf16 row-major (pre-transposed).
#define LP 40   // padded LDS row length (bf16 elems) for 32-k tiles
template <int BN>
__global__ __launch_bounds__(256) void gemm_mfma(const float* __restrict__ A,
                                                 const ushort* __restrict__ Bt,
                                                 const float* __restrict__ bias,
                                                 ushort* __restrict__ C,
                                                 int M, int K, int Kp, int Cstride, int col0) {
    __shared__ ushort As[128 * LP];
    __shared__ ushort Bs[BN * LP];
    const int t = threadIdx.x;
    const int r0 = blockIdx.x * 128;
    const int lane = t & 63;
    const int w = t >> 6;
    const int la = lane & 15;
    const int lk = (lane >> 4) * 8;

    constexpr int MR = (BN == 128) ? 4 : 2;
    const int m0 = (BN == 128) ? (w >> 1) * 64 : w * 32;
    const int n0 = (BN == 128) ? (w & 1) * 64 : 0;

    f32x4 acc[MR][4];
#pragma unroll
    for (int i = 0; i < MR; ++i)
#pragma unroll
        for (int j = 0; j < 4; ++j) acc[i][j] = (f32x4)0.f;

    const int sr = t >> 1;            // A/B stage row 0..127
    const int skh = (t & 1) * 16;     // k-half
    const float* Ap = A + (size_t)(r0 + sr) * K;
    const bool rowok = (r0 + sr) < M;
    const bool vecA = (K == Kp);      // K%4==0 and no tail -> aligned float4 loads

    for (int k0 = 0; k0 < Kp; k0 += 32) {
        // ---- stage A (f32 -> bf16) ----
        alignas(16) ushort ta[16];
        if (vecA) {
            if (rowok) {
#pragma unroll
                for (int q = 0; q < 4; ++q) {
                    float4 v = *(const float4*)(Ap + k0 + skh + q * 4);
                    ta[q * 4 + 0] = f2bf(v.x); ta[q * 4 + 1] = f2bf(v.y);
                    ta[q * 4 + 2] = f2bf(v.z); ta[q * 4 + 3] = f2bf(v.w);
                }
            } else {
#pragma unroll
                for (int j = 0; j < 16; ++j) ta[j] = 0;
            }
        } else {
#pragma unroll
            for (int j = 0; j < 16; ++j) {
                int k = k0 + skh + j;
                float v = (rowok && k < K) ? Ap[k] : 0.f;
                ta[j] = f2bf(v);
            }
        }
        *(uint4*)&As[sr * LP + skh] = ((const uint4*)ta)[0];
        *(uint4*)&As[sr * LP + skh + 8] = ((const uint4*)ta)[1];
        // ---- stage B ----
        if (BN == 128) {
            const ushort* Bp = Bt + (size_t)sr * Kp + k0 + skh;
            *(uint4*)&Bs[sr * LP + skh] = ((const uint4*)Bp)[0];
            *(uint4*)&Bs[sr * LP + skh + 8] = ((const uint4*)Bp)[1];
        } else {
            int n = t >> 2, kq = (t & 3) * 8;
            const ushort* Bp = Bt + (size_t)n * Kp + k0 + kq;
            *(uint4*)&Bs[n * LP + kq] = *(const uint4*)Bp;
        }
        __syncthreads();
        // ---- MFMA ----
        s16x8 av[MR], bv[4];
#pragma unroll
        for (int i = 0; i < MR; ++i)
            av[i] = *(const s16x8*)&As[(m0 + i * 16 + la) * LP + lk];
#pragma unroll
        for (int j = 0; j < 4; ++j)
            bv[j] = *(const s16x8*)&Bs[(n0 + j * 16 + la) * LP + lk];
#pragma unroll
        for (int i = 0; i < MR; ++i)
#pragma unroll
            for (int j = 0; j < 4; ++j)
                acc[i][j] = __builtin_amdgcn_mfma_f32_16x16x32_bf16(av[i], bv[j], acc[i][j], 0, 0, 0);
        __syncthreads();
    }
    // ---- epilogue: bf16 store + bias ----
    const int lrow = (lane >> 4) * 4;
#pragma unroll
    for (int i = 0; i < MR; ++i) {
#pragma unroll
        for (int j = 0; j < 4; ++j) {
            int col = n0 + j * 16 + la;
            float bval = bias[col];
#pragma unroll
            for (int r = 0; r < 4; ++r) {
                int row = r0 + m0 + i * 16 + lrow + r;
                if (row < M) C[(size_t)row * Cstride + col0 + col] = f2bf(acc[i][j][r] + bval);
            }
        }
    }
}

// ---------------- GATv2 aggregation: one wave per node, bf16 gathers ----------------
template <int CPL, bool RBF16>
__global__ __launch_bounds__(256) void gat_agg(const ushort* __restrict__ xcat, int xstride,
                                               int xr_off,
                                               const void* __restrict__ resv, int rstride, int roff,
                                               const float* __restrict__ att,
                                               const float* __restrict__ bias,
                                               const int* __restrict__ rowptr,
                                               const int* __restrict__ csr,
                                               float* __restrict__ hout, int hstride, int M) {
    int n = blockIdx.x * 4 + (threadIdx.x >> 6);
    if (n >= M) return;
    int t = threadIdx.x & 63;

    float xr0, xr1 = 0.f, at0, at1 = 0.f;
    if (CPL == 2) {
        uint u = *(const uint*)(xcat + (size_t)n * xstride + xr_off + 2 * t);
        xr0 = bflo(u); xr1 = bfhi(u);
        float2 a2 = *(const float2*)(att + 2 * t);
        at0 = a2.x; at1 = a2.y;
    } else {
        xr0 = bf2f(xcat[(size_t)n * xstride + xr_off + t]);
        at0 = att[t];
    }

    int s0 = rowptr[n], s1 = rowptr[n + 1];
    float ssum = 0.f, a0 = 0.f, a1 = 0.f;
    if (s1 > s0) {
        int sp = csr[s0];
        float c0, c1 = 0.f;
        if (CPL == 2) {
            uint u = *(const uint*)(xcat + (size_t)sp * xstride + 2 * t);
            c0 = bflo(u); c1 = bfhi(u);
        } else {
            c0 = bf2f(xcat[(size_t)sp * xstride + t]);
        }
        for (int i = s0; i < s1; ++i) {
            float x0 = c0, x1 = c1;
            if (i + 1 < s1) {
                int spn = csr[i + 1];
                if (CPL == 2) {
                    uint u = *(const uint*)(xcat + (size_t)spn * xstride + 2 * t);
                    c0 = bflo(u); c1 = bfhi(u);
                } else {
                    c0 = bf2f(xcat[(size_t)spn * xstride + t]);
                }
            }
            float v0 = x0 + xr0, v1 = x1 + xr1;
            float l0 = v0 > 0.f ? v0 : 0.2f * v0;
            float l1 = v1 > 0.f ? v1 : 0.2f * v1;
            float prod = (CPL == 2) ? fmaf(l1, at1, l0 * at0) : l0 * at0;
            prod += __shfl_xor(prod, 1);
            prod += __shfl_xor(prod, 2);
            prod += __shfl_xor(prod, 4);
            float p = __expf(prod);
            ssum += p;
            a0 = fmaf(p, x0, a0);
            a1 = fmaf(p, x1, a1);
        }
    }
    float inv = 1.f / (ssum + 1e-16f);
    if (CPL == 2) {
        float r0v, r1v;
        if (RBF16) {
            uint u = *(const uint*)((const ushort*)resv + (size_t)n * rstride + roff + 2 * t);
            r0v = bflo(u); r1v = bfhi(u);
        } else {
            float2 rr = *(const float2*)((const float*)resv + (size_t)n * rstride + roff + 2 * t);
            r0v = rr.x; r1v = rr.y;
        }
        float2 bs = *(const float2*)(bias + 2 * t);
        float y0 = fmaf(a0, inv, bs.x + r0v);
        float y1 = fmaf(a1, inv, bs.y + r1v);
        float o0 = 0.5f * y0 * (1.f + erff(y0 * 0.70710678118654752f));
        float o1 = 0.5f * y1 * (1.f + erff(y1 * 0.70710678118654752f));
        *(float2*)(hout + (size_t)n * hstride + 2 * t) = make_float2(o0, o1);
    } else {
        float rv;
        if (RBF16) rv = bf2f(((const ushort*)resv)[(size_t)n * rstride + roff + t]);
        else       rv = ((const float*)resv)[(size_t)n * rstride + roff + t];
        float y0 = fmaf(a0, inv, bias[t] + rv);
        float o0 = 0.5f * y0 * (1.f + erff(y0 * 0.70710678118654752f));
        hout[(size_t)n * hstride + t] = o0;
    }
}

// ---------------- final linear 64 -> 32 ----------------
__global__ __launch_bounds__(256) void final_linear(const float* __restrict__ h,
                                                    const float* __restrict__ W,
                                                    const float* __restrict__ b,
                                                    float* __restrict__ out, int M) {
    __shared__ float Ws[64 * 32];
    __shared__ float bs[32];
    __shared__ float hs[8][64];
    int t = threadIdx.x;
    for (int i = t; i < 64 * 32; i += 256) Ws[i] = W[i];
    if (t < 32) bs[t] = b[t];
    int r0 = blockIdx.x * 8;
    for (int i = t; i < 8 * 64; i += 256) {
        int r = i >> 6, c = i & 63;
        hs[r][c] = (r0 + r < M) ? h[(size_t)(r0 + r) * 64 + c] : 0.f;
    }
    __syncthreads();
    int lr = t >> 5;
    int col = t & 31;
    int row = r0 + lr;
    if (row >= M) return;
    float acc = bs[col];
#pragma unroll 8
    for (int k = 0; k < 64; ++k) acc += hs[lr][k] * Ws[k * 32 + col];
    out[(size_t)row * 32 + col] = acc;
}

extern "C" void kernel_launch(void* const* d_in, const int* in_sizes, int n_in,
                              void* d_out, int out_size, void* d_ws, size_t ws_size,
                              hipStream_t stream) {
    const float* x = (const float*)d_in[0];
    const int* ei = (const int*)d_in[1];
    const int E = in_sizes[1] / 2;
    const int* srcp = ei;
    const int* dstp = ei + E;

    const float* Wl[4]  = {(const float*)d_in[2],  (const float*)d_in[8],  (const float*)d_in[14], (const float*)d_in[20]};
    const float* bl[4]  = {(const float*)d_in[3],  (const float*)d_in[9],  (const float*)d_in[15], (const float*)d_in[21]};
    const float* Wr[4]  = {(const float*)d_in[4],  (const float*)d_in[10], (const float*)d_in[16], (const float*)d_in[22]};
    const float* br[4]  = {(const float*)d_in[5],  (const float*)d_in[11], (const float*)d_in[17], (const float*)d_in[23]};
    const float* att[4] = {(const float*)d_in[6],  (const float*)d_in[12], (const float*)d_in[18], (const float*)d_in[24]};
    const float* bia[4] = {(const float*)d_in[7],  (const float*)d_in[13], (const float*)d_in[19], (const float*)d_in[25]};
    const float* proj1W = (const float*)d_in[26];
    const float* proj1b = (const float*)d_in[27];
    const float* proj4W = (const float*)d_in[28];
    const float* proj4b = (const float*)d_in[29];
    const float* linW   = (const float*)d_in[30];
    const float* linb   = (const float*)d_in[31];

    const int M = NNODES;
    // ---- workspace layout ----
    ushort* xcat = (ushort*)d_ws;                         // up to [M,384] bf16
    float* h  = (float*)(xcat + (size_t)M * 384);         // [M,128] f32
    float* h4 = h + (size_t)M * 128;                      // [M,64] f32
    ushort* wb = (ushort*)(h4 + (size_t)M * 64);
    ushort* WtL1 = wb; wb += 128 * 224;
    ushort* WtR1 = wb; wb += 128 * 224;
    ushort* WtP1 = wb; wb += 128 * 224;
    ushort* WtL2 = wb; wb += 128 * 128;
    ushort* WtR2 = wb; wb += 128 * 128;
    ushort* WtL3 = wb; wb += 128 * 128;
    ushort* WtR3 = wb; wb += 128 * 128;
    ushort* WtL4 = wb; wb += 64 * 128;
    ushort* WtR4 = wb; wb += 64 * 128;
    ushort* WtP4 = wb; wb += 64 * 128;
    int* deg    = (int*)wb;
    int* cursor = deg + M;
    int* rowptr = cursor + M;
    int* csr    = rowptr + (M + 1);

    // ---- CSR build ----
    hipMemsetAsync(deg, 0, 2 * (size_t)M * sizeof(int), stream);
    hist_kernel<<<(E + 255) / 256, 256, 0, stream>>>(dstp, E, deg);
    scan_kernel<<<1, 1024, 0, stream>>>(deg, rowptr, M);
    scatter_kernel<<<(E + 255) / 256, 256, 0, stream>>>(srcp, dstp, E, rowptr, cursor, csr);

    // ---- weight conversion (10 weights, one kernel) ----
    WConvArgs wa;
    wa.d[0] = {Wl[0],  WtL1, 193, 128, 224};
    wa.d[1] = {Wr[0],  WtR1, 193, 128, 224};
    wa.d[2] = {proj1W, WtP1, 193, 128, 224};
    wa.d[3] = {Wl[1],  WtL2, 128, 128, 128};
    wa.d[4] = {Wr[1],  WtR2, 128, 128, 128};
    wa.d[5] = {Wl[2],  WtL3, 128, 128, 128};
    wa.d[6] = {Wr[2],  WtR3, 128, 128, 128};
    wa.d[7] = {Wl[3],  WtL4, 128, 64, 128};
    wa.d[8] = {Wr[3],  WtR4, 128, 64, 128};
    wa.d[9] = {proj4W, WtP4, 128, 64, 128};
    convert_weights<<<dim3(112, 10), 256, 0, stream>>>(wa);

    dim3 gg((M + 127) / 128, 1);
    dim3 ag((M + 3) / 4, 1);

    // ---- layer 1: fin=193 (Kp=224), HC=128; xcat = [xl|xr|res] bf16, stride 384 ----
    gemm_mfma<128><<<gg, 256, 0, stream>>>(x, WtL1, bl[0], xcat, M, 193, 224, 384, 0);
    gemm_mfma<128><<<gg, 256, 0, stream>>>(x, WtR1, br[0], xcat, M, 193, 224, 384, 128);
    gemm_mfma<128><<<gg, 256, 0, stream>>>(x, WtP1, proj1b, xcat, M, 193, 224, 384, 256);
    gat_agg<2, true><<<ag, 256, 0, stream>>>(xcat, 384, 128, xcat, 384, 256, att[0], bia[0],
                                             rowptr, csr, h, 128, M);
    // ---- layer 2: stride 256, residual = h (f32) ----
    gemm_mfma<128><<<gg, 256, 0, stream>>>(h, WtL2, bl[1], xcat, M, 128, 128, 256, 0);
    gemm_mfma<128><<<gg, 256, 0, stream>>>(h, WtR2, br[1], xcat, M, 128, 128, 256, 128);
    gat_agg<2, false><<<ag, 256, 0, stream>>>(xcat, 256, 128, h, 128, 0, att[1], bia[1],
                                              rowptr, csr, h, 128, M);
    // ---- layer 3 ----
    gemm_mfma<128><<<gg, 256, 0, stream>>>(h, WtL3, bl[2], xcat, M, 128, 128, 256, 0);
    gemm_mfma<128><<<gg, 256, 0, stream>>>(h, WtR3, br[2], xcat, M, 128, 128, 256, 128);
    gat_agg<2, false><<<ag, 256, 0, stream>>>(xcat, 256, 128, h, 128, 0, att[2], bia[2],
                                              rowptr, csr, h, 128, M);
    // ---- layer 4: HC=64; xcat = [xl|xr|res] bf16, stride 192 ----
    gemm_mfma<64><<<gg, 256, 0, stream>>>(h, WtL4, bl[3], xcat, M, 128, 128, 192, 0);
    gemm_mfma<64><<<gg, 256, 0, stream>>>(h, WtR4, br[3], xcat, M, 128, 128, 192, 64);
    gemm_mfma<64><<<gg, 256, 0, stream>>>(h, WtP4, proj4b, xcat, M, 128, 128, 192, 128);
    gat_agg<1, true><<<ag, 256, 0, stream>>>(xcat, 192, 64, xcat, 192, 128, att[3], bia[3],
                                             rowptr, csr, h4, 64, M);
    // ---- final linear 64 -> 32 ----
    final_linear<<<(M + 7) / 8, 256, 0, stream>>>(h4, linW, linb, (float*)d_out, M);
}

// Round 4
// 1011.594 us; speedup vs baseline: 2.1388x; 1.4242x over previous
//
#include <hip/hip_runtime.h>
#include <hip/hip_bf16.h>

#define NNODES 100000

typedef short s16x8 __attribute__((ext_vector_type(8)));
typedef float f32x4 __attribute__((ext_vector_type(4)));

__device__ inline ushort f2bf(float f) {   // round-to-nearest-even
    uint u = __float_as_uint(f);
    uint r = u + 0x7fffu + ((u >> 16) & 1u);
    return (ushort)(r >> 16);
}
__device__ inline float bf2f(ushort u) { return __uint_as_float(((uint)u) << 16); }
__device__ inline float bflo(uint u) { return __uint_as_float(u << 16); }
__device__ inline float bfhi(uint u) { return __uint_as_float(u & 0xffff0000u); }

// ---------------- CSR build ----------------
__global__ void hist_kernel(const int* __restrict__ dst, int E, int* __restrict__ deg) {
    int e = blockIdx.x * blockDim.x + threadIdx.x;
    if (e < E) atomicAdd(&deg[dst[e]], 1);
}

__global__ __launch_bounds__(1024) void scan_kernel(const int* __restrict__ deg,
                                                    int* __restrict__ rowptr, int n) {
    __shared__ int part[1024];
    int t = threadIdx.x;
    int chunk = (n + 1023) >> 10;
    int start = t * chunk;
    int end = min(start + chunk, n);
    int s = 0;
    for (int i = start; i < end; ++i) s += deg[i];
    part[t] = s;
    __syncthreads();
    for (int off = 1; off < 1024; off <<= 1) {
        int v = (t >= off) ? part[t - off] : 0;
        __syncthreads();
        part[t] += v;
        __syncthreads();
    }
    int run = (t == 0) ? 0 : part[t - 1];
    for (int i = start; i < end; ++i) { rowptr[i] = run; run += deg[i]; }
    if (t == 1023) rowptr[n] = run;
}

__global__ void scatter_kernel(const int* __restrict__ src, const int* __restrict__ dst, int E,
                               const int* __restrict__ rowptr, int* __restrict__ cursor,
                               int* __restrict__ csr) {
    int e = blockIdx.x * blockDim.x + threadIdx.x;
    if (e < E) {
        int d = dst[e];
        int pos = rowptr[d] + atomicAdd(&cursor[d], 1);
        csr[pos] = src[e];
    }
}

// ---------------- weight conversion: W[K,N] f32 -> Wt[N,Kp] bf16 (transposed, K zero-padded) ----------------
struct WConvDesc { const float* W; ushort* Wt; int K, N, Kp; };
struct WConvArgs { WConvDesc d[10]; };

__global__ void convert_weights(WConvArgs args) {
    WConvDesc dd = args.d[blockIdx.y];
    int total = dd.N * dd.Kp;
    for (int i = blockIdx.x * 256 + threadIdx.x; i < total; i += gridDim.x * 256) {
        int n = i / dd.Kp, k = i - n * dd.Kp;
        float v = (k < dd.K) ? dd.W[(size_t)k * dd.N + n] : 0.f;
        dd.Wt[i] = f2bf(v);
    }
}

// ---------------- MFMA GEMM: C[:, col0:col0+BN] (bf16, strided) = A[M,K] f32 @ Wt^T + bias ----------------
#define LP 40   // padded LDS row length (bf16 elems) for 32-k tiles
template <int BN>
__global__ __launch_bounds__(256) void gemm_mfma(const float* __restrict__ A,
                                                 const ushort* __restrict__ Bt,
                                                 const float* __restrict__ bias,
                                                 ushort* __restrict__ C,
                                                 int M, int K, int Kp, int Cstride, int col0) {
    __shared__ ushort As[128 * LP];
    __shared__ ushort Bs[BN * LP];
    const int t = threadIdx.x;
    const int r0 = blockIdx.x * 128;
    const int lane = t & 63;
    const int w = t >> 6;
    const int la = lane & 15;
    const int lk = (lane >> 4) * 8;

    constexpr int MR = (BN == 128) ? 4 : 2;
    const int m0 = (BN == 128) ? (w >> 1) * 64 : w * 32;
    const int n0 = (BN == 128) ? (w & 1) * 64 : 0;

    f32x4 acc[MR][4];
#pragma unroll
    for (int i = 0; i < MR; ++i)
#pragma unroll
        for (int j = 0; j < 4; ++j) acc[i][j] = (f32x4)0.f;

    const int sr = t >> 1;
    const int skh = (t & 1) * 16;
    const float* Ap = A + (size_t)(r0 + sr) * K;
    const bool rowok = (r0 + sr) < M;
    const bool vecA = (K == Kp);

    for (int k0 = 0; k0 < Kp; k0 += 32) {
        alignas(16) ushort ta[16];
        if (vecA) {
            if (rowok) {
#pragma unroll
                for (int q = 0; q < 4; ++q) {
                    float4 v = *(const float4*)(Ap + k0 + skh + q * 4);
                    ta[q * 4 + 0] = f2bf(v.x); ta[q * 4 + 1] = f2bf(v.y);
                    ta[q * 4 + 2] = f2bf(v.z); ta[q * 4 + 3] = f2bf(v.w);
                }
            } else {
#pragma unroll
                for (int j = 0; j < 16; ++j) ta[j] = 0;
            }
        } else {
#pragma unroll
            for (int j = 0; j < 16; ++j) {
                int k = k0 + skh + j;
                float v = (rowok && k < K) ? Ap[k] : 0.f;
                ta[j] = f2bf(v);
            }
        }
        *(uint4*)&As[sr * LP + skh] = ((const uint4*)ta)[0];
        *(uint4*)&As[sr * LP + skh + 8] = ((const uint4*)ta)[1];
        if (BN == 128) {
            const ushort* Bp = Bt + (size_t)sr * Kp + k0 + skh;
            *(uint4*)&Bs[sr * LP + skh] = ((const uint4*)Bp)[0];
            *(uint4*)&Bs[sr * LP + skh + 8] = ((const uint4*)Bp)[1];
        } else {
            int n = t >> 2, kq = (t & 3) * 8;
            const ushort* Bp = Bt + (size_t)n * Kp + k0 + kq;
            *(uint4*)&Bs[n * LP + kq] = *(const uint4*)Bp;
        }
        __syncthreads();
        s16x8 av[MR], bv[4];
#pragma unroll
        for (int i = 0; i < MR; ++i)
            av[i] = *(const s16x8*)&As[(m0 + i * 16 + la) * LP + lk];
#pragma unroll
        for (int j = 0; j < 4; ++j)
            bv[j] = *(const s16x8*)&Bs[(n0 + j * 16 + la) * LP + lk];
#pragma unroll
        for (int i = 0; i < MR; ++i)
#pragma unroll
            for (int j = 0; j < 4; ++j)
                acc[i][j] = __builtin_amdgcn_mfma_f32_16x16x32_bf16(av[i], bv[j], acc[i][j], 0, 0, 0);
        __syncthreads();
    }
    const int lrow = (lane >> 4) * 4;
#pragma unroll
    for (int i = 0; i < MR; ++i) {
#pragma unroll
        for (int j = 0; j < 4; ++j) {
            int col = n0 + j * 16 + la;
            float bval = bias[col];
#pragma unroll
            for (int r = 0; r < 4; ++r) {
                int row = r0 + m0 + i * 16 + lrow + r;
                if (row < M) C[(size_t)row * Cstride + col0 + col] = f2bf(acc[i][j][r] + bval);
            }
        }
    }
}

// ---------------- GATv2 aggregation: one wave per node, 2 edges/iter, 4-deep pipeline ----------------
// Lanes 0-31 handle even edges, 32-63 odd edges; lane holds CPL channels (CPL=4 -> HC=128).
// Head spans 4 lanes in both configs (CPL=4: C=16; CPL=2: C=8) -> shfl_xor 1,2 reduce.
// Max-free softmax (scores bounded) => halves merge by addition at the end.
template <int CPL, bool RBF16>
__global__ __launch_bounds__(256) void gat_agg(const ushort* __restrict__ xcat, int xstride,
                                               int xr_off,
                                               const void* __restrict__ resv, int rstride, int roff,
                                               const float* __restrict__ att,
                                               const float* __restrict__ bias,
                                               const int* __restrict__ rowptr,
                                               const int* __restrict__ csr,
                                               float* __restrict__ hout, int hstride, int M) {
    int n = blockIdx.x * 4 + (threadIdx.x >> 6);
    if (n >= M) return;
    const int lane = threadIdx.x & 63;
    const int half = lane >> 5;
    const int c = lane & 31;

    float xr[CPL], at[CPL];
    if (CPL == 4) {
        uint2 u = *(const uint2*)(xcat + (size_t)n * xstride + xr_off + 4 * c);
        xr[0] = bflo(u.x); xr[1] = bfhi(u.x); xr[2] = bflo(u.y); xr[3] = bfhi(u.y);
        float4 a = *(const float4*)(att + 4 * c);
        at[0] = a.x; at[1] = a.y; at[2] = a.z; at[3] = a.w;
    } else {
        uint u = *(const uint*)(xcat + (size_t)n * xstride + xr_off + 2 * c);
        xr[0] = bflo(u); xr[1] = bfhi(u);
        float2 a = *(const float2*)(att + 2 * c);
        at[0] = a.x; at[1] = a.y;
    }

    const int s0 = rowptr[n], s1 = rowptr[n + 1];
    float ssum = 0.f;
    float acc[CPL];
#pragma unroll
    for (int j = 0; j < CPL; ++j) acc[j] = 0.f;

    for (int cs = s0; cs < s1; cs += 64) {
        const int cnt = min(64, s1 - cs);
        const int pairs = (cnt + 1) >> 1;
        const int ci = csr[min(cs + lane, s1 - 1)];   // coalesced; indices live in registers

        auto ISSUE = [&](uint2& buf, bool& v, int p) {
            if (p >= pairs) { v = false; buf.x = 0u; buf.y = 0u; return; }
            int idx = 2 * p + half;
            v = idx < cnt;
            int src = __shfl(ci, min(idx, cnt - 1));
            const ushort* rp = xcat + (size_t)src * xstride + ((CPL == 4) ? 4 * c : 2 * c);
            if (CPL == 4) buf = *(const uint2*)rp;
            else          buf.x = *(const uint*)rp;
        };
        auto COMPUTE = [&](const uint2& buf, bool v) {
            float x[CPL];
            x[0] = bflo(buf.x); x[1] = bfhi(buf.x);
            if (CPL == 4) { x[2] = bflo(buf.y); x[3] = bfhi(buf.y); }
            float prod;
            {
                float l[CPL];
#pragma unroll
                for (int j = 0; j < CPL; ++j) {
                    float vv = x[j] + xr[j];
                    l[j] = fmaxf(vv, 0.2f * vv);     // leaky relu, slope < 1
                }
                prod = l[0] * at[0];
#pragma unroll
                for (int j = 1; j < CPL; ++j) prod = fmaf(l[j], at[j], prod);
            }
            prod += __shfl_xor(prod, 1);
            prod += __shfl_xor(prod, 2);
            float pe = v ? __expf(prod) : 0.f;
            ssum += pe;
#pragma unroll
            for (int j = 0; j < CPL; ++j) acc[j] = fmaf(pe, x[j], acc[j]);
        };

        uint2 bA, bB, bC, bD;
        bool vA, vB, vC, vD;
        ISSUE(bA, vA, 0); ISSUE(bB, vB, 1); ISSUE(bC, vC, 2); ISSUE(bD, vD, 3);
        for (int p = 0; p < pairs; p += 4) {
            COMPUTE(bA, vA); ISSUE(bA, vA, p + 4);
            if (p + 1 < pairs) { COMPUTE(bB, vB); ISSUE(bB, vB, p + 5); }
            if (p + 2 < pairs) { COMPUTE(bC, vC); ISSUE(bC, vC, p + 6); }
            if (p + 3 < pairs) { COMPUTE(bD, vD); ISSUE(bD, vD, p + 7); }
        }
    }

    // merge the two half-wave partials (pure sums: no max tracking)
    ssum += __shfl_xor(ssum, 32);
#pragma unroll
    for (int j = 0; j < CPL; ++j) acc[j] += __shfl_xor(acc[j], 32);

    if (half == 0) {
        float inv = 1.f / (ssum + 1e-16f);
        float r[CPL], bb[CPL], o[CPL];
        if (CPL == 4) {
            if (RBF16) {
                uint2 u = *(const uint2*)((const ushort*)resv + (size_t)n * rstride + roff + 4 * c);
                r[0] = bflo(u.x); r[1] = bfhi(u.x); r[2] = bflo(u.y); r[3] = bfhi(u.y);
            } else {
                float4 rr = *(const float4*)((const float*)resv + (size_t)n * rstride + roff + 4 * c);
                r[0] = rr.x; r[1] = rr.y; r[2] = rr.z; r[3] = rr.w;
            }
            float4 b4 = *(const float4*)(bias + 4 * c);
            bb[0] = b4.x; bb[1] = b4.y; bb[2] = b4.z; bb[3] = b4.w;
        } else {
            if (RBF16) {
                uint u = *(const uint*)((const ushort*)resv + (size_t)n * rstride + roff + 2 * c);
                r[0] = bflo(u); r[1] = bfhi(u);
            } else {
                float2 rr = *(const float2*)((const float*)resv + (size_t)n * rstride + roff + 2 * c);
                r[0] = rr.x; r[1] = rr.y;
            }
            float2 b2 = *(const float2*)(bias + 2 * c);
            bb[0] = b2.x; bb[1] = b2.y;
        }
#pragma unroll
        for (int j = 0; j < CPL; ++j) {
            float y = fmaf(acc[j], inv, bb[j] + r[j]);
            o[j] = 0.5f * y * (1.f + erff(y * 0.70710678118654752f));
        }
        if (CPL == 4)
            *(float4*)(hout + (size_t)n * hstride + 4 * c) = make_float4(o[0], o[1], o[2], o[3]);
        else
            *(float2*)(hout + (size_t)n * hstride + 2 * c) = make_float2(o[0], o[1]);
    }
}

// ---------------- final linear 64 -> 32 ----------------
__global__ __launch_bounds__(256) void final_linear(const float* __restrict__ h,
                                                    const float* __restrict__ W,
                                                    const float* __restrict__ b,
                                                    float* __restrict__ out, int M) {
    __shared__ float Ws[64 * 32];
    __shared__ float bs[32];
    __shared__ float hs[8][64];
    int t = threadIdx.x;
    for (int i = t; i < 64 * 32; i += 256) Ws[i] = W[i];
    if (t < 32) bs[t] = b[t];
    int r0 = blockIdx.x * 8;
    for (int i = t; i < 8 * 64; i += 256) {
        int r = i >> 6, c = i & 63;
        hs[r][c] = (r0 + r < M) ? h[(size_t)(r0 + r) * 64 + c] : 0.f;
    }
    __syncthreads();
    int lr = t >> 5;
    int col = t & 31;
    int row = r0 + lr;
    if (row >= M) return;
    float acc = bs[col];
#pragma unroll 8
    for (int k = 0; k < 64; ++k) acc += hs[lr][k] * Ws[k * 32 + col];
    out[(size_t)row * 32 + col] = acc;
}

extern "C" void kernel_launch(void* const* d_in, const int* in_sizes, int n_in,
                              void* d_out, int out_size, void* d_ws, size_t ws_size,
                              hipStream_t stream) {
    const float* x = (const float*)d_in[0];
    const int* ei = (const int*)d_in[1];
    const int E = in_sizes[1] / 2;
    const int* srcp = ei;
    const int* dstp = ei + E;

    const float* Wl[4]  = {(const float*)d_in[2],  (const float*)d_in[8],  (const float*)d_in[14], (const float*)d_in[20]};
    const float* bl[4]  = {(const float*)d_in[3],  (const float*)d_in[9],  (const float*)d_in[15], (const float*)d_in[21]};
    const float* Wr[4]  = {(const float*)d_in[4],  (const float*)d_in[10], (const float*)d_in[16], (const float*)d_in[22]};
    const float* br[4]  = {(const float*)d_in[5],  (const float*)d_in[11], (const float*)d_in[17], (const float*)d_in[23]};
    const float* att[4] = {(const float*)d_in[6],  (const float*)d_in[12], (const float*)d_in[18], (const float*)d_in[24]};
    const float* bia[4] = {(const float*)d_in[7],  (const float*)d_in[13], (const float*)d_in[19], (const float*)d_in[25]};
    const float* proj1W = (const float*)d_in[26];
    const float* proj1b = (const float*)d_in[27];
    const float* proj4W = (const float*)d_in[28];
    const float* proj4b = (const float*)d_in[29];
    const float* linW   = (const float*)d_in[30];
    const float* linb   = (const float*)d_in[31];

    const int M = NNODES;
    ushort* xcat = (ushort*)d_ws;                         // up to [M,384] bf16
    float* h  = (float*)(xcat + (size_t)M * 384);         // [M,128] f32
    float* h4 = h + (size_t)M * 128;                      // [M,64] f32
    ushort* wb = (ushort*)(h4 + (size_t)M * 64);
    ushort* WtL1 = wb; wb += 128 * 224;
    ushort* WtR1 = wb; wb += 128 * 224;
    ushort* WtP1 = wb; wb += 128 * 224;
    ushort* WtL2 = wb; wb += 128 * 128;
    ushort* WtR2 = wb; wb += 128 * 128;
    ushort* WtL3 = wb; wb += 128 * 128;
    ushort* WtR3 = wb; wb += 128 * 128;
    ushort* WtL4 = wb; wb += 64 * 128;
    ushort* WtR4 = wb; wb += 64 * 128;
    ushort* WtP4 = wb; wb += 64 * 128;
    int* deg    = (int*)wb;
    int* cursor = deg + M;
    int* rowptr = cursor + M;
    int* csr    = rowptr + (M + 1);

    // ---- CSR build ----
    hipMemsetAsync(deg, 0, 2 * (size_t)M * sizeof(int), stream);
    hist_kernel<<<(E + 255) / 256, 256, 0, stream>>>(dstp, E, deg);
    scan_kernel<<<1, 1024, 0, stream>>>(deg, rowptr, M);
    scatter_kernel<<<(E + 255) / 256, 256, 0, stream>>>(srcp, dstp, E, rowptr, cursor, csr);

    // ---- weight conversion ----
    WConvArgs wa;
    wa.d[0] = {Wl[0],  WtL1, 193, 128, 224};
    wa.d[1] = {Wr[0],  WtR1, 193, 128, 224};
    wa.d[2] = {proj1W, WtP1, 193, 128, 224};
    wa.d[3] = {Wl[1],  WtL2, 128, 128, 128};
    wa.d[4] = {Wr[1],  WtR2, 128, 128, 128};
    wa.d[5] = {Wl[2],  WtL3, 128, 128, 128};
    wa.d[6] = {Wr[2],  WtR3, 128, 128, 128};
    wa.d[7] = {Wl[3],  WtL4, 128, 64, 128};
    wa.d[8] = {Wr[3],  WtR4, 128, 64, 128};
    wa.d[9] = {proj4W, WtP4, 128, 64, 128};
    convert_weights<<<dim3(112, 10), 256, 0, stream>>>(wa);

    dim3 gg((M + 127) / 128, 1);
    dim3 ag((M + 3) / 4, 1);

    // ---- layer 1: fin=193 (Kp=224), HC=128; xcat = [xl|xr|res] bf16, stride 384 ----
    gemm_mfma<128><<<gg, 256, 0, stream>>>(x, WtL1, bl[0], xcat, M, 193, 224, 384, 0);
    gemm_mfma<128><<<gg, 256, 0, stream>>>(x, WtR1, br[0], xcat, M, 193, 224, 384, 128);
    gemm_mfma<128><<<gg, 256, 0, stream>>>(x, WtP1, proj1b, xcat, M, 193, 224, 384, 256);
    gat_agg<4, true><<<ag, 256, 0, stream>>>(xcat, 384, 128, xcat, 384, 256, att[0], bia[0],
                                             rowptr, csr, h, 128, M);
    // ---- layer 2: stride 256, residual = h (f32) ----
    gemm_mfma<128><<<gg, 256, 0, stream>>>(h, WtL2, bl[1], xcat, M, 128, 128, 256, 0);
    gemm_mfma<128><<<gg, 256, 0, stream>>>(h, WtR2, br[1], xcat, M, 128, 128, 256, 128);
    gat_agg<4, false><<<ag, 256, 0, stream>>>(xcat, 256, 128, h, 128, 0, att[1], bia[1],
                                              rowptr, csr, h, 128, M);
    // ---- layer 3 ----
    gemm_mfma<128><<<gg, 256, 0, stream>>>(h, WtL3, bl[2], xcat, M, 128, 128, 256, 0);
    gemm_mfma<128><<<gg, 256, 0, stream>>>(h, WtR3, br[2], xcat, M, 128, 128, 256, 128);
    gat_agg<4, false><<<ag, 256, 0, stream>>>(xcat, 256, 128, h, 128, 0, att[2], bia[2],
                                              rowptr, csr, h, 128, M);
    // ---- layer 4: HC=64; xcat = [xl|xr|res] bf16, stride 192 ----
    gemm_mfma<64><<<gg, 256, 0, stream>>>(h, WtL4, bl[3], xcat, M, 128, 128, 192, 0);
    gemm_mfma<64><<<gg, 256, 0, stream>>>(h, WtR4, br[3], xcat, M, 128, 128, 192, 64);
    gemm_mfma<64><<<gg, 256, 0, stream>>>(h, WtP4, proj4b, xcat, M, 128, 128, 192, 128);
    gat_agg<2, true><<<ag, 256, 0, stream>>>(xcat, 192, 64, xcat, 192, 128, att[3], bia[3],
                                             rowptr, csr, h4, 64, M);
    // ---- final linear 64 -> 32 ----
    final_linear<<<(M + 7) / 8, 256, 0, stream>>>(h4, linW, linb, (float*)d_out, M);
}

// Round 5
// 748.572 us; speedup vs baseline: 2.8903x; 1.3514x over previous
//
#include <hip/hip_runtime.h>
#include <hip/hip_bf16.h>

#define NNODES 100000

typedef short s16x8 __attribute__((ext_vector_type(8)));
typedef float f32x4 __attribute__((ext_vector_type(4)));

__device__ inline ushort f2bf(float f) {   // round-to-nearest-even
    uint u = __float_as_uint(f);
    uint r = u + 0x7fffu + ((u >> 16) & 1u);
    return (ushort)(r >> 16);
}
__device__ inline float bf2f(ushort u) { return __uint_as_float(((uint)u) << 16); }
__device__ inline float bflo(uint u) { return __uint_as_float(u << 16); }
__device__ inline float bfhi(uint u) { return __uint_as_float(u & 0xffff0000u); }

// ---------------- CSR build ----------------
__global__ void hist_kernel(const int* __restrict__ dst, int E, int* __restrict__ deg) {
    int e = blockIdx.x * blockDim.x + threadIdx.x;
    if (e < E) atomicAdd(&deg[dst[e]], 1);
}

// 3-phase multi-block exclusive scan over deg[n] -> rowptr[n+1]
__global__ __launch_bounds__(256) void scan_part(const int* __restrict__ deg,
                                                 int* __restrict__ bsum, int n) {
    int t = threadIdx.x;
    int base = blockIdx.x * 1024 + t * 4;
    int4 v = make_int4(0, 0, 0, 0);
    if (base + 3 < n) v = *(const int4*)(deg + base);
    else {
        if (base + 0 < n) v.x = deg[base + 0];
        if (base + 1 < n) v.y = deg[base + 1];
        if (base + 2 < n) v.z = deg[base + 2];
    }
    int s = v.x + v.y + v.z + v.w;
#pragma unroll
    for (int o = 1; o < 64; o <<= 1) s += __shfl_xor(s, o);
    __shared__ int ws[4];
    if ((t & 63) == 0) ws[t >> 6] = s;
    __syncthreads();
    if (t == 0) bsum[blockIdx.x] = ws[0] + ws[1] + ws[2] + ws[3];
}

__global__ __launch_bounds__(128) void scan_bsum(int* __restrict__ bsum, int nb,
                                                 int* __restrict__ rowptr, int n) {
    __shared__ int s[128];
    int t = threadIdx.x;
    int v = (t < nb) ? bsum[t] : 0;
    s[t] = v;
    __syncthreads();
#pragma unroll
    for (int o = 1; o < 128; o <<= 1) {
        int u = (t >= o) ? s[t - o] : 0;
        __syncthreads();
        s[t] += u;
        __syncthreads();
    }
    if (t < nb) bsum[t] = s[t] - v;      // exclusive
    if (t == 127) rowptr[n] = s[127];    // total
}

__global__ __launch_bounds__(256) void scan_apply(const int* __restrict__ deg,
                                                  const int* __restrict__ bsum,
                                                  int* __restrict__ rowptr, int n) {
    int t = threadIdx.x;
    int base = blockIdx.x * 1024 + t * 4;
    int4 v = make_int4(0, 0, 0, 0);
    if (base + 3 < n) v = *(const int4*)(deg + base);
    else {
        if (base + 0 < n) v.x = deg[base + 0];
        if (base + 1 < n) v.y = deg[base + 1];
        if (base + 2 < n) v.z = deg[base + 2];
    }
    int s = v.x + v.y + v.z + v.w;
    int lane = t & 63, w = t >> 6;
    int incl = s;
#pragma unroll
    for (int o = 1; o < 64; o <<= 1) {
        int u = __shfl_up(incl, o);
        if (lane >= o) incl += u;
    }
    __shared__ int wsum[4];
    if (lane == 63) wsum[w] = incl;
    __syncthreads();
    int woff = 0;
    if (w > 0) woff += wsum[0];
    if (w > 1) woff += wsum[1];
    if (w > 2) woff += wsum[2];
    int off = bsum[blockIdx.x] + woff + (incl - s);
    int4 r;
    r.x = off;
    r.y = off + v.x;
    r.z = r.y + v.y;
    r.w = r.z + v.z;
    if (base + 3 < n) *(int4*)(rowptr + base) = r;
    else {
        if (base + 0 < n) rowptr[base + 0] = r.x;
        if (base + 1 < n) rowptr[base + 1] = r.y;
        if (base + 2 < n) rowptr[base + 2] = r.z;
    }
}

__global__ void scatter_kernel(const int* __restrict__ src, const int* __restrict__ dst, int E,
                               const int* __restrict__ rowptr, int* __restrict__ cursor,
                               int* __restrict__ csr) {
    int e = blockIdx.x * blockDim.x + threadIdx.x;
    if (e < E) {
        int d = dst[e];
        int pos = rowptr[d] + atomicAdd(&cursor[d], 1);
        csr[pos] = src[e];
    }
}

// ---------------- weight conversion: W[K,N] f32 -> Wt[N,Kp] bf16 (transposed, K zero-padded) ----------------
struct WConvDesc { const float* W; ushort* Wt; int K, N, Kp; };
struct WConvArgs { WConvDesc d[10]; };

__global__ void convert_weights(WConvArgs args) {
    WConvDesc dd = args.d[blockIdx.y];
    int total = dd.N * dd.Kp;
    for (int i = blockIdx.x * 256 + threadIdx.x; i < total; i += gridDim.x * 256) {
        int n = i / dd.Kp, k = i - n * dd.Kp;
        float v = (k < dd.K) ? dd.W[(size_t)k * dd.N + n] : 0.f;
        dd.Wt[i] = f2bf(v);
    }
}

// ---------------- x conversion: x[M,193] f32 -> xb[M,224] bf16 (padded) ----------------
__global__ void convert_x(const float* __restrict__ x, ushort* __restrict__ xb, int M) {
    int total = M * 56;   // groups of 4 output elems
    for (int i = blockIdx.x * 256 + threadIdx.x; i < total; i += gridDim.x * 256) {
        int n = i / 56;
        int k4 = (i - n * 56) * 4;
        ushort o[4];
#pragma unroll
        for (int j = 0; j < 4; ++j) {
            int k = k4 + j;
            o[j] = (k < 193) ? f2bf(x[(size_t)n * 193 + k]) : (ushort)0;
        }
        *(uint2*)(xb + (size_t)n * 224 + k4) = *(const uint2*)o;
    }
}

// ---------------- MFMA GEMM: C[:, col0:col0+BN] (bf16, strided) = A[M,Kp] bf16 @ Wt^T + bias ----------------
#define LP 40   // padded LDS row length (bf16 elems) for 32-k tiles
template <int BN>
__global__ __launch_bounds__(256) void gemm_mfma(const ushort* __restrict__ A,
                                                 const ushort* __restrict__ Bt,
                                                 const float* __restrict__ bias,
                                                 ushort* __restrict__ C,
                                                 int M, int Kp, int Cstride, int col0) {
    __shared__ ushort As[128 * LP];
    __shared__ ushort Bs[BN * LP];
    const int t = threadIdx.x;
    const int r0 = blockIdx.x * 128;
    const int lane = t & 63;
    const int w = t >> 6;
    const int la = lane & 15;
    const int lk = (lane >> 4) * 8;

    constexpr int MR = (BN == 128) ? 4 : 2;
    const int m0 = (BN == 128) ? (w >> 1) * 64 : w * 32;
    const int n0 = (BN == 128) ? (w & 1) * 64 : 0;

    f32x4 acc[MR][4];
#pragma unroll
    for (int i = 0; i < MR; ++i)
#pragma unroll
        for (int j = 0; j < 4; ++j) acc[i][j] = (f32x4)0.f;

    const int sr = t >> 1;
    const int skh = (t & 1) * 16;
    const ushort* Ap = A + (size_t)(r0 + sr) * Kp;
    const bool rowok = (r0 + sr) < M;

    for (int k0 = 0; k0 < Kp; k0 += 32) {
        uint4 a0 = make_uint4(0u, 0u, 0u, 0u), a1 = a0;
        if (rowok) {
            const ushort* p = Ap + k0 + skh;
            a0 = ((const uint4*)p)[0];
            a1 = ((const uint4*)p)[1];
        }
        *(uint4*)&As[sr * LP + skh] = a0;
        *(uint4*)&As[sr * LP + skh + 8] = a1;
        if (BN == 128) {
            const ushort* Bp = Bt + (size_t)sr * Kp + k0 + skh;
            *(uint4*)&Bs[sr * LP + skh] = ((const uint4*)Bp)[0];
            *(uint4*)&Bs[sr * LP + skh + 8] = ((const uint4*)Bp)[1];
        } else {
            int nr = t >> 2, kq = (t & 3) * 8;
            const ushort* Bp = Bt + (size_t)nr * Kp + k0 + kq;
            *(uint4*)&Bs[nr * LP + kq] = *(const uint4*)Bp;
        }
        __syncthreads();
        s16x8 av[MR], bv[4];
#pragma unroll
        for (int i = 0; i < MR; ++i)
            av[i] = *(const s16x8*)&As[(m0 + i * 16 + la) * LP + lk];
#pragma unroll
        for (int j = 0; j < 4; ++j)
            bv[j] = *(const s16x8*)&Bs[(n0 + j * 16 + la) * LP + lk];
#pragma unroll
        for (int i = 0; i < MR; ++i)
#pragma unroll
            for (int j = 0; j < 4; ++j)
                acc[i][j] = __builtin_amdgcn_mfma_f32_16x16x32_bf16(av[i], bv[j], acc[i][j], 0, 0, 0);
        __syncthreads();
    }
    const int lrow = (lane >> 4) * 4;
#pragma unroll
    for (int i = 0; i < MR; ++i) {
#pragma unroll
        for (int j = 0; j < 4; ++j) {
            int col = n0 + j * 16 + la;
            float bval = bias[col];
#pragma unroll
            for (int r = 0; r < 4; ++r) {
                int row = r0 + m0 + i * 16 + lrow + r;
                if (row < M) C[(size_t)row * Cstride + col0 + col] = f2bf(acc[i][j][r] + bval);
            }
        }
    }
}

// ---------------- GATv2 aggregation: one wave per node, 2 edges/iter, 8-deep pipeline ----------------
template <int CPL, bool RBF16>
__global__ __launch_bounds__(256) void gat_agg(const ushort* __restrict__ xcat, int xstride,
                                               int xr_off,
                                               const void* __restrict__ resv, int rstride, int roff,
                                               const float* __restrict__ att,
                                               const float* __restrict__ bias,
                                               const int* __restrict__ rowptr,
                                               const int* __restrict__ csr,
                                               float* __restrict__ hout, int hstride,
                                               ushort* __restrict__ houtb, int M) {
    int n = blockIdx.x * 4 + (threadIdx.x >> 6);
    if (n >= M) return;
    const int lane = threadIdx.x & 63;
    const int half = lane >> 5;
    const int c = lane & 31;

    float xr[CPL], at[CPL];
    if (CPL == 4) {
        uint2 u = *(const uint2*)(xcat + (size_t)n * xstride + xr_off + 4 * c);
        xr[0] = bflo(u.x); xr[1] = bfhi(u.x); xr[2] = bflo(u.y); xr[3] = bfhi(u.y);
        float4 a = *(const float4*)(att + 4 * c);
        at[0] = a.x; at[1] = a.y; at[2] = a.z; at[3] = a.w;
    } else {
        uint u = *(const uint*)(xcat + (size_t)n * xstride + xr_off + 2 * c);
        xr[0] = bflo(u); xr[1] = bfhi(u);
        float2 a = *(const float2*)(att + 2 * c);
        at[0] = a.x; at[1] = a.y;
    }

    const int s0 = rowptr[n], s1 = rowptr[n + 1];
    float ssum = 0.f;
    float acc[CPL];
#pragma unroll
    for (int j = 0; j < CPL; ++j) acc[j] = 0.f;

    for (int cs = s0; cs < s1; cs += 64) {
        const int cnt = min(64, s1 - cs);
        const int pairs = (cnt + 1) >> 1;
        const int ci = csr[min(cs + lane, s1 - 1)];   // coalesced; indices live in registers

        auto ISSUE = [&](uint2& buf, bool& v, int p) {
            if (p >= pairs) { v = false; buf.x = 0u; buf.y = 0u; return; }
            int idx = 2 * p + half;
            v = idx < cnt;
            int src = __shfl(ci, min(idx, cnt - 1));
            const ushort* rp = xcat + (size_t)src * xstride + ((CPL == 4) ? 4 * c : 2 * c);
            if (CPL == 4) buf = *(const uint2*)rp;
            else          buf.x = *(const uint*)rp;
        };
        auto COMPUTE = [&](const uint2& buf, bool v) {
            float x[CPL];
            x[0] = bflo(buf.x); x[1] = bfhi(buf.x);
            if (CPL == 4) { x[2] = bflo(buf.y); x[3] = bfhi(buf.y); }
            float prod;
            {
                float l[CPL];
#pragma unroll
                for (int j = 0; j < CPL; ++j) {
                    float vv = x[j] + xr[j];
                    l[j] = fmaxf(vv, 0.2f * vv);
                }
                prod = l[0] * at[0];
#pragma unroll
                for (int j = 1; j < CPL; ++j) prod = fmaf(l[j], at[j], prod);
            }
            prod += __shfl_xor(prod, 1);
            prod += __shfl_xor(prod, 2);
            float pe = v ? __expf(prod) : 0.f;
            ssum += pe;
#pragma unroll
            for (int j = 0; j < CPL; ++j) acc[j] = fmaf(pe, x[j], acc[j]);
        };

        uint2 b0, b1, b2, b3, b4, b5, b6, b7;
        bool v0, v1, v2, v3, v4, v5, v6, v7;
        ISSUE(b0, v0, 0); ISSUE(b1, v1, 1); ISSUE(b2, v2, 2); ISSUE(b3, v3, 3);
        ISSUE(b4, v4, 4); ISSUE(b5, v5, 5); ISSUE(b6, v6, 6); ISSUE(b7, v7, 7);
        for (int p = 0; p < pairs; p += 8) {
            COMPUTE(b0, v0); ISSUE(b0, v0, p + 8);
            if (p + 1 < pairs) { COMPUTE(b1, v1); ISSUE(b1, v1, p + 9); }
            if (p + 2 < pairs) { COMPUTE(b2, v2); ISSUE(b2, v2, p + 10); }
            if (p + 3 < pairs) { COMPUTE(b3, v3); ISSUE(b3, v3, p + 11); }
            if (p + 4 < pairs) { COMPUTE(b4, v4); ISSUE(b4, v4, p + 12); }
            if (p + 5 < pairs) { COMPUTE(b5, v5); ISSUE(b5, v5, p + 13); }
            if (p + 6 < pairs) { COMPUTE(b6, v6); ISSUE(b6, v6, p + 14); }
            if (p + 7 < pairs) { COMPUTE(b7, v7); ISSUE(b7, v7, p + 15); }
        }
    }

    // merge the two half-wave partials (pure sums: no max tracking)
    ssum += __shfl_xor(ssum, 32);
#pragma unroll
    for (int j = 0; j < CPL; ++j) acc[j] += __shfl_xor(acc[j], 32);

    if (half == 0) {
        float inv = 1.f / (ssum + 1e-16f);
        float r[CPL], bb[CPL], o[CPL];
        if (CPL == 4) {
            if (RBF16) {
                uint2 u = *(const uint2*)((const ushort*)resv + (size_t)n * rstride + roff + 4 * c);
                r[0] = bflo(u.x); r[1] = bfhi(u.x); r[2] = bflo(u.y); r[3] = bfhi(u.y);
            } else {
                float4 rr = *(const float4*)((const float*)resv + (size_t)n * rstride + roff + 4 * c);
                r[0] = rr.x; r[1] = rr.y; r[2] = rr.z; r[3] = rr.w;
            }
            float4 b4v = *(const float4*)(bias + 4 * c);
            bb[0] = b4v.x; bb[1] = b4v.y; bb[2] = b4v.z; bb[3] = b4v.w;
        } else {
            if (RBF16) {
                uint u = *(const uint*)((const ushort*)resv + (size_t)n * rstride + roff + 2 * c);
                r[0] = bflo(u); r[1] = bfhi(u);
            } else {
                float2 rr = *(const float2*)((const float*)resv + (size_t)n * rstride + roff + 2 * c);
                r[0] = rr.x; r[1] = rr.y;
            }
            float2 b2v = *(const float2*)(bias + 2 * c);
            bb[0] = b2v.x; bb[1] = b2v.y;
        }
#pragma unroll
        for (int j = 0; j < CPL; ++j) {
            float y = fmaf(acc[j], inv, bb[j] + r[j]);
            o[j] = 0.5f * y * (1.f + erff(y * 0.70710678118654752f));
        }
        if (CPL == 4) {
            if (hout)
                *(float4*)(hout + (size_t)n * hstride + 4 * c) = make_float4(o[0], o[1], o[2], o[3]);
            if (houtb) {
                uint2 pk;
                pk.x = (uint)f2bf(o[0]) | ((uint)f2bf(o[1]) << 16);
                pk.y = (uint)f2bf(o[2]) | ((uint)f2bf(o[3]) << 16);
                *(uint2*)(houtb + (size_t)n * 128 + 4 * c) = pk;
            }
        } else {
            if (hout)
                *(float2*)(hout + (size_t)n * hstride + 2 * c) = make_float2(o[0], o[1]);
            if (houtb) {
                uint pk = (uint)f2bf(o[0]) | ((uint)f2bf(o[1]) << 16);
                *(uint*)(houtb + (size_t)n * 64 + 2 * c) = pk;
            }
        }
    }
}

// ---------------- final linear 64 -> 32 ----------------
__global__ __launch_bounds__(256) void final_linear(const float* __restrict__ h,
                                                    const float* __restrict__ W,
                                                    const float* __restrict__ b,
                                                    float* __restrict__ out, int M) {
    __shared__ float Ws[64 * 32];
    __shared__ float bs[32];
    __shared__ float hs[8][64];
    int t = threadIdx.x;
    for (int i = t; i < 64 * 32; i += 256) Ws[i] = W[i];
    if (t < 32) bs[t] = b[t];
    int r0 = blockIdx.x * 8;
    for (int i = t; i < 8 * 64; i += 256) {
        int r = i >> 6, c = i & 63;
        hs[r][c] = (r0 + r < M) ? h[(size_t)(r0 + r) * 64 + c] : 0.f;
    }
    __syncthreads();
    int lr = t >> 5;
    int col = t & 31;
    int row = r0 + lr;
    if (row >= M) return;
    float acc = bs[col];
#pragma unroll 8
    for (int k = 0; k < 64; ++k) acc += hs[lr][k] * Ws[k * 32 + col];
    out[(size_t)row * 32 + col] = acc;
}

extern "C" void kernel_launch(void* const* d_in, const int* in_sizes, int n_in,
                              void* d_out, int out_size, void* d_ws, size_t ws_size,
                              hipStream_t stream) {
    const float* x = (const float*)d_in[0];
    const int* ei = (const int*)d_in[1];
    const int E = in_sizes[1] / 2;
    const int* srcp = ei;
    const int* dstp = ei + E;

    const float* Wl[4]  = {(const float*)d_in[2],  (const float*)d_in[8],  (const float*)d_in[14], (const float*)d_in[20]};
    const float* bl[4]  = {(const float*)d_in[3],  (const float*)d_in[9],  (const float*)d_in[15], (const float*)d_in[21]};
    const float* Wr[4]  = {(const float*)d_in[4],  (const float*)d_in[10], (const float*)d_in[16], (const float*)d_in[22]};
    const float* br[4]  = {(const float*)d_in[5],  (const float*)d_in[11], (const float*)d_in[17], (const float*)d_in[23]};
    const float* att[4] = {(const float*)d_in[6],  (const float*)d_in[12], (const float*)d_in[18], (const float*)d_in[24]};
    const float* bia[4] = {(const float*)d_in[7],  (const float*)d_in[13], (const float*)d_in[19], (const float*)d_in[25]};
    const float* proj1W = (const float*)d_in[26];
    const float* proj1b = (const float*)d_in[27];
    const float* proj4W = (const float*)d_in[28];
    const float* proj4b = (const float*)d_in[29];
    const float* linW   = (const float*)d_in[30];
    const float* linb   = (const float*)d_in[31];

    const int M = NNODES;
    // ---- workspace layout (bf16 A path; hb aliases xb after layer-1 GEMMs) ----
    ushort* xcat = (ushort*)d_ws;                         // [M,384] bf16 max
    ushort* xb   = xcat + (size_t)M * 384;                // [M,224] bf16 (x padded); later hb [M,128]
    ushort* hb   = xb;                                    // alias: bf16 h for next-layer GEMM A
    float* h  = (float*)(xb + (size_t)M * 224);           // [M,128] f32
    float* h4 = h + (size_t)M * 128;                      // [M,64] f32
    ushort* wb = (ushort*)(h4 + (size_t)M * 64);
    ushort* WtL1 = wb; wb += 128 * 224;
    ushort* WtR1 = wb; wb += 128 * 224;
    ushort* WtP1 = wb; wb += 128 * 224;
    ushort* WtL2 = wb; wb += 128 * 128;
    ushort* WtR2 = wb; wb += 128 * 128;
    ushort* WtL3 = wb; wb += 128 * 128;
    ushort* WtR3 = wb; wb += 128 * 128;
    ushort* WtL4 = wb; wb += 64 * 128;
    ushort* WtR4 = wb; wb += 64 * 128;
    ushort* WtP4 = wb; wb += 64 * 128;
    int* deg    = (int*)wb;
    int* cursor = deg + M;
    int* rowptr = cursor + M;
    int* csr    = rowptr + (M + 1);
    int* bsum   = csr + E;           // 98 ints

    const int NB = (M + 1023) / 1024;    // 98

    // ---- CSR build ----
    hipMemsetAsync(deg, 0, 2 * (size_t)M * sizeof(int), stream);
    hist_kernel<<<(E + 255) / 256, 256, 0, stream>>>(dstp, E, deg);
    scan_part<<<NB, 256, 0, stream>>>(deg, bsum, M);
    scan_bsum<<<1, 128, 0, stream>>>(bsum, NB, rowptr, M);
    scan_apply<<<NB, 256, 0, stream>>>(deg, bsum, rowptr, M);
    scatter_kernel<<<(E + 255) / 256, 256, 0, stream>>>(srcp, dstp, E, rowptr, cursor, csr);

    // ---- weight + x conversion ----
    WConvArgs wa;
    wa.d[0] = {Wl[0],  WtL1, 193, 128, 224};
    wa.d[1] = {Wr[0],  WtR1, 193, 128, 224};
    wa.d[2] = {proj1W, WtP1, 193, 128, 224};
    wa.d[3] = {Wl[1],  WtL2, 128, 128, 128};
    wa.d[4] = {Wr[1],  WtR2, 128, 128, 128};
    wa.d[5] = {Wl[2],  WtL3, 128, 128, 128};
    wa.d[6] = {Wr[2],  WtR3, 128, 128, 128};
    wa.d[7] = {Wl[3],  WtL4, 128, 64, 128};
    wa.d[8] = {Wr[3],  WtR4, 128, 64, 128};
    wa.d[9] = {proj4W, WtP4, 128, 64, 128};
    convert_weights<<<dim3(112, 10), 256, 0, stream>>>(wa);
    convert_x<<<2048, 256, 0, stream>>>(x, xb, M);

    dim3 gg((M + 127) / 128, 1);
    dim3 ag((M + 3) / 4, 1);

    // ---- layer 1: Kp=224, HC=128; xcat = [xl|xr|res] bf16, stride 384 ----
    gemm_mfma<128><<<gg, 256, 0, stream>>>(xb, WtL1, bl[0], xcat, M, 224, 384, 0);
    gemm_mfma<128><<<gg, 256, 0, stream>>>(xb, WtR1, br[0], xcat, M, 224, 384, 128);
    gemm_mfma<128><<<gg, 256, 0, stream>>>(xb, WtP1, proj1b, xcat, M, 224, 384, 256);
    gat_agg<4, true><<<ag, 256, 0, stream>>>(xcat, 384, 128, xcat, 384, 256, att[0], bia[0],
                                             rowptr, csr, h, 128, hb, M);
    // ---- layer 2: stride 256, residual = h (f32) ----
    gemm_mfma<128><<<gg, 256, 0, stream>>>(hb, WtL2, bl[1], xcat, M, 128, 256, 0);
    gemm_mfma<128><<<gg, 256, 0, stream>>>(hb, WtR2, br[1], xcat, M, 128, 256, 128);
    gat_agg<4, false><<<ag, 256, 0, stream>>>(xcat, 256, 128, h, 128, 0, att[1], bia[1],
                                              rowptr, csr, h, 128, hb, M);
    // ---- layer 3 (f32 h no longer needed downstream -> skip f32 write) ----
    gemm_mfma<128><<<gg, 256, 0, stream>>>(hb, WtL3, bl[2], xcat, M, 128, 256, 0);
    gemm_mfma<128><<<gg, 256, 0, stream>>>(hb, WtR3, br[2], xcat, M, 128, 256, 128);
    gat_agg<4, false><<<ag, 256, 0, stream>>>(xcat, 256, 128, h, 128, 0, att[2], bia[2],
                                              rowptr, csr, nullptr, 128, hb, M);
    // ---- layer 4: HC=64; xcat = [xl|xr|res] bf16, stride 192 ----
    gemm_mfma<64><<<gg, 256, 0, stream>>>(hb, WtL4, bl[3], xcat, M, 128, 192, 0);
    gemm_mfma<64><<<gg, 256, 0, stream>>>(hb, WtR4, br[3], xcat, M, 128, 192, 64);
    gemm_mfma<64><<<gg, 256, 0, stream>>>(hb, WtP4, proj4b, xcat, M, 128, 192, 128);
    gat_agg<2, true><<<ag, 256, 0, stream>>>(xcat, 192, 64, xcat, 192, 128, att[3], bia[3],
                                             rowptr, csr, h4, 64, nullptr, M);
    // ---- final linear 64 -> 32 ----
    final_linear<<<(M + 7) / 8, 256, 0, stream>>>(h4, linW, linb, (float*)d_out, M);
}

// Round 6
// 681.666 us; speedup vs baseline: 3.1740x; 1.0982x over previous
//
#include <hip/hip_runtime.h>
#include <hip/hip_bf16.h>

#define NNODES 100000

typedef short s16x8 __attribute__((ext_vector_type(8)));
typedef float f32x4 __attribute__((ext_vector_type(4)));

__device__ inline ushort f2bf(float f) {   // round-to-nearest-even
    uint u = __float_as_uint(f);
    uint r = u + 0x7fffu + ((u >> 16) & 1u);
    return (ushort)(r >> 16);
}
__device__ inline float bf2f(ushort u) { return __uint_as_float(((uint)u) << 16); }
__device__ inline float bflo(uint u) { return __uint_as_float(u << 16); }
__device__ inline float bfhi(uint u) { return __uint_as_float(u & 0xffff0000u); }

// ---------------- CSR build ----------------
__global__ void hist_kernel(const int* __restrict__ dst, int E, int* __restrict__ deg) {
    int e = blockIdx.x * blockDim.x + threadIdx.x;
    if (e < E) atomicAdd(&deg[dst[e]], 1);
}

__global__ __launch_bounds__(256) void scan_part(const int* __restrict__ deg,
                                                 int* __restrict__ bsum, int n) {
    int t = threadIdx.x;
    int base = blockIdx.x * 1024 + t * 4;
    int4 v = make_int4(0, 0, 0, 0);
    if (base + 3 < n) v = *(const int4*)(deg + base);
    else {
        if (base + 0 < n) v.x = deg[base + 0];
        if (base + 1 < n) v.y = deg[base + 1];
        if (base + 2 < n) v.z = deg[base + 2];
    }
    int s = v.x + v.y + v.z + v.w;
#pragma unroll
    for (int o = 1; o < 64; o <<= 1) s += __shfl_xor(s, o);
    __shared__ int ws[4];
    if ((t & 63) == 0) ws[t >> 6] = s;
    __syncthreads();
    if (t == 0) bsum[blockIdx.x] = ws[0] + ws[1] + ws[2] + ws[3];
}

__global__ __launch_bounds__(128) void scan_bsum(int* __restrict__ bsum, int nb,
                                                 int* __restrict__ rowptr, int n) {
    __shared__ int s[128];
    int t = threadIdx.x;
    int v = (t < nb) ? bsum[t] : 0;
    s[t] = v;
    __syncthreads();
#pragma unroll
    for (int o = 1; o < 128; o <<= 1) {
        int u = (t >= o) ? s[t - o] : 0;
        __syncthreads();
        s[t] += u;
        __syncthreads();
    }
    if (t < nb) bsum[t] = s[t] - v;      // exclusive
    if (t == 127) rowptr[n] = s[127];    // total
}

__global__ __launch_bounds__(256) void scan_apply(const int* __restrict__ deg,
                                                  const int* __restrict__ bsum,
                                                  int* __restrict__ rowptr, int n) {
    int t = threadIdx.x;
    int base = blockIdx.x * 1024 + t * 4;
    int4 v = make_int4(0, 0, 0, 0);
    if (base + 3 < n) v = *(const int4*)(deg + base);
    else {
        if (base + 0 < n) v.x = deg[base + 0];
        if (base + 1 < n) v.y = deg[base + 1];
        if (base + 2 < n) v.z = deg[base + 2];
    }
    int s = v.x + v.y + v.z + v.w;
    int lane = t & 63, w = t >> 6;
    int incl = s;
#pragma unroll
    for (int o = 1; o < 64; o <<= 1) {
        int u = __shfl_up(incl, o);
        if (lane >= o) incl += u;
    }
    __shared__ int wsum[4];
    if (lane == 63) wsum[w] = incl;
    __syncthreads();
    int woff = 0;
    if (w > 0) woff += wsum[0];
    if (w > 1) woff += wsum[1];
    if (w > 2) woff += wsum[2];
    int off = bsum[blockIdx.x] + woff + (incl - s);
    int4 r;
    r.x = off;
    r.y = off + v.x;
    r.z = r.y + v.y;
    r.w = r.z + v.z;
    if (base + 3 < n) *(int4*)(rowptr + base) = r;
    else {
        if (base + 0 < n) rowptr[base + 0] = r.x;
        if (base + 1 < n) rowptr[base + 1] = r.y;
        if (base + 2 < n) rowptr[base + 2] = r.z;
    }
}

__global__ void scatter_kernel(const int* __restrict__ src, const int* __restrict__ dst, int E,
                               const int* __restrict__ rowptr, int* __restrict__ cursor,
                               int* __restrict__ csr) {
    int e = blockIdx.x * blockDim.x + threadIdx.x;
    if (e < E) {
        int d = dst[e];
        int pos = rowptr[d] + atomicAdd(&cursor[d], 1);
        csr[pos] = src[e];
    }
}

// ---------------- weight conversion: W[K,N] f32 -> Wt[N,Kp] bf16 (transposed, K zero-padded) ----------------
struct WConvDesc { const float* W; ushort* Wt; int K, N, Kp; };
struct WConvArgs { WConvDesc d[10]; };

__global__ void convert_weights(WConvArgs args) {
    WConvDesc dd = args.d[blockIdx.y];
    int total = dd.N * dd.Kp;
    for (int i = blockIdx.x * 256 + threadIdx.x; i < total; i += gridDim.x * 256) {
        int n = i / dd.Kp, k = i - n * dd.Kp;
        float v = (k < dd.K) ? dd.W[(size_t)k * dd.N + n] : 0.f;
        dd.Wt[i] = f2bf(v);
    }
}

struct BCat { const float* src; float* dst; int len; };
struct BCatArgs { BCat d[10]; };
__global__ void concat_bias(BCatArgs a) {
    BCat dd = a.d[blockIdx.x];
    for (int i = threadIdx.x; i < dd.len; i += 256) dd.dst[i] = dd.src[i];
}

// ---------------- x conversion: x[M,193] f32 -> xb[M,224] bf16 (padded) ----------------
__global__ void convert_x(const float* __restrict__ x, ushort* __restrict__ xb, int M) {
    int total = M * 56;   // groups of 4 output elems
    for (int i = blockIdx.x * 256 + threadIdx.x; i < total; i += gridDim.x * 256) {
        int n = i / 56;
        int k4 = (i - n * 56) * 4;
        ushort o[4];
#pragma unroll
        for (int j = 0; j < 4; ++j) {
            int k = k4 + j;
            o[j] = (k < 193) ? f2bf(x[(size_t)n * 193 + k]) : (ushort)0;
        }
        *(uint2*)(xb + (size_t)n * 224 + k4) = *(const uint2*)o;
    }
}

// ---------------- MFMA GEMM: C[:, col0:col0+BN] = A bf16 @ Wt^T + bias; col0 = blockIdx.y*BN ----------------
#define LP 40   // padded LDS row length (bf16 elems)
template <int BN>
__global__ __launch_bounds__(256) void gemm_mfma(const ushort* __restrict__ A,
                                                 const ushort* __restrict__ BtAll,
                                                 const float* __restrict__ biasAll,
                                                 ushort* __restrict__ C,
                                                 int M, int Kp, int Cstride) {
    const int col0 = blockIdx.y * BN;
    const ushort* Bt = BtAll + (size_t)col0 * Kp;
    const float* bias = biasAll + col0;

    __shared__ ushort As[128 * LP];
    __shared__ ushort Bs[BN * LP];
    const int t = threadIdx.x;
    const int r0 = blockIdx.x * 128;
    const int lane = t & 63;
    const int w = t >> 6;
    const int la = lane & 15;
    const int lk = (lane >> 4) * 8;

    constexpr int MR = (BN == 128) ? 4 : 2;
    const int m0 = (BN == 128) ? (w >> 1) * 64 : w * 32;
    const int n0 = (BN == 128) ? (w & 1) * 64 : 0;

    f32x4 acc[MR][4];
#pragma unroll
    for (int i = 0; i < MR; ++i)
#pragma unroll
        for (int j = 0; j < 4; ++j) acc[i][j] = (f32x4)0.f;

    const int sr = t >> 1;
    const int skh = (t & 1) * 16;
    const ushort* Ap = A + (size_t)(r0 + sr) * Kp;
    const bool rowok = (r0 + sr) < M;

    for (int k0 = 0; k0 < Kp; k0 += 32) {
        uint4 a0 = make_uint4(0u, 0u, 0u, 0u), a1 = a0;
        if (rowok) {
            const ushort* p = Ap + k0 + skh;
            a0 = ((const uint4*)p)[0];
            a1 = ((const uint4*)p)[1];
        }
        *(uint4*)&As[sr * LP + skh] = a0;
        *(uint4*)&As[sr * LP + skh + 8] = a1;
        if (BN == 128) {
            const ushort* Bp = Bt + (size_t)sr * Kp + k0 + skh;
            *(uint4*)&Bs[sr * LP + skh] = ((const uint4*)Bp)[0];
            *(uint4*)&Bs[sr * LP + skh + 8] = ((const uint4*)Bp)[1];
        } else {
            int nr = t >> 2, kq = (t & 3) * 8;
            const ushort* Bp = Bt + (size_t)nr * Kp + k0 + kq;
            *(uint4*)&Bs[nr * LP + kq] = *(const uint4*)Bp;
        }
        __syncthreads();
        s16x8 av[MR], bv[4];
#pragma unroll
        for (int i = 0; i < MR; ++i)
            av[i] = *(const s16x8*)&As[(m0 + i * 16 + la) * LP + lk];
#pragma unroll
        for (int j = 0; j < 4; ++j)
            bv[j] = *(const s16x8*)&Bs[(n0 + j * 16 + la) * LP + lk];
#pragma unroll
        for (int i = 0; i < MR; ++i)
#pragma unroll
            for (int j = 0; j < 4; ++j)
                acc[i][j] = __builtin_amdgcn_mfma_f32_16x16x32_bf16(av[i], bv[j], acc[i][j], 0, 0, 0);
        __syncthreads();
    }
    const int lrow = (lane >> 4) * 4;
#pragma unroll
    for (int i = 0; i < MR; ++i) {
#pragma unroll
        for (int j = 0; j < 4; ++j) {
            int col = n0 + j * 16 + la;
            float bval = bias[col];
#pragma unroll
            for (int r = 0; r < 4; ++r) {
                int row = r0 + m0 + i * 16 + lrow + r;
                if (row < M) C[(size_t)row * Cstride + col0 + col] = f2bf(acc[i][j][r] + bval);
            }
        }
    }
}

// ---------------- GATv2 aggregation: one wave/node, 8 ch/lane (16B gathers), EPI edges/iter ----------------
// HC=128: 16 lanes/edge, 4 edges/iter, head spans 2 lanes (shfl_xor 1).
// HC=64 :  8 lanes/edge, 8 edges/iter, head = 1 lane (no reduce).
template <int HC, bool RBF16>
__global__ __launch_bounds__(256) void gat_agg(const ushort* __restrict__ xcat, int xstride,
                                               int xr_off,
                                               const void* __restrict__ resv, int rstride, int roff,
                                               const float* __restrict__ att,
                                               const float* __restrict__ bias,
                                               const int* __restrict__ rowptr,
                                               const int* __restrict__ csr,
                                               float* __restrict__ hout, int hstride,
                                               ushort* __restrict__ houtb, int M) {
    constexpr int LPE = HC / 8;       // lanes per edge
    constexpr int EPI = 64 / LPE;     // edges per iteration
    constexpr int QSH = (HC == 128) ? 4 : 3;
    const int n = blockIdx.x * 4 + (threadIdx.x >> 6);
    if (n >= M) return;
    const int lane = threadIdx.x & 63;
    const int clane = lane & (LPE - 1);
    const int q = lane >> QSH;

    const char* xb = (const char*)xcat;
    const uint xrowB = (uint)xstride * 2u;
    const uint chB = (uint)clane * 16u;

    float xr[8], at[8];
    {
        uint4 u = *(const uint4*)(xb + (uint)n * xrowB + (uint)xr_off * 2u + chB);
        xr[0] = bflo(u.x); xr[1] = bfhi(u.x); xr[2] = bflo(u.y); xr[3] = bfhi(u.y);
        xr[4] = bflo(u.z); xr[5] = bfhi(u.z); xr[6] = bflo(u.w); xr[7] = bfhi(u.w);
        float4 a0 = *(const float4*)(att + 8 * clane);
        float4 a1 = *(const float4*)(att + 8 * clane + 4);
        at[0] = a0.x; at[1] = a0.y; at[2] = a0.z; at[3] = a0.w;
        at[4] = a1.x; at[5] = a1.y; at[6] = a1.z; at[7] = a1.w;
    }

    const int s0 = rowptr[n], s1 = rowptr[n + 1];
    float ssum = 0.f;
    float acc[8] = {0.f, 0.f, 0.f, 0.f, 0.f, 0.f, 0.f, 0.f};

    if (s1 > s0) {
        const int nq = (s1 - s0 + EPI - 1) >> (6 - QSH);   // ceil-div by EPI
        auto ISSUE = [&](uint4& buf, bool& val, int p) {
            if (p >= nq) { val = false; buf = make_uint4(0u, 0u, 0u, 0u); return; }
            int g = s0 + p * EPI + q;
            val = g < s1;
            int src = csr[min(g, s1 - 1)];       // wave-uniform per slot -> L1 broadcast
            buf = *(const uint4*)(xb + (uint)src * xrowB + chB);
        };
        auto COMPUTE = [&](const uint4& buf, bool val) {
            float x[8];
            x[0] = bflo(buf.x); x[1] = bfhi(buf.x); x[2] = bflo(buf.y); x[3] = bfhi(buf.y);
            x[4] = bflo(buf.z); x[5] = bfhi(buf.z); x[6] = bflo(buf.w); x[7] = bfhi(buf.w);
            float prod = 0.f;
#pragma unroll
            for (int j = 0; j < 8; ++j) {
                float v = x[j] + xr[j];
                float l = fmaxf(v, 0.2f * v);
                prod = fmaf(l, at[j], prod);
            }
            if constexpr (HC == 128) prod += __shfl_xor(prod, 1);
            float pe = val ? __expf(prod) : 0.f;
            ssum += pe;
#pragma unroll
            for (int j = 0; j < 8; ++j) acc[j] = fmaf(pe, x[j], acc[j]);
        };
        uint4 b0, b1, b2, b3;
        bool v0, v1, v2, v3;
        ISSUE(b0, v0, 0); ISSUE(b1, v1, 1); ISSUE(b2, v2, 2); ISSUE(b3, v3, 3);
        for (int p = 0; p < nq; p += 4) {
            COMPUTE(b0, v0); ISSUE(b0, v0, p + 4);
            if (p + 1 < nq) { COMPUTE(b1, v1); ISSUE(b1, v1, p + 5); }
            if (p + 2 < nq) { COMPUTE(b2, v2); ISSUE(b2, v2, p + 6); }
            if (p + 3 < nq) { COMPUTE(b3, v3); ISSUE(b3, v3, p + 7); }
        }
    }

    // merge partials across edge slots (butterfly over q bits)
#pragma unroll
    for (int o = LPE; o < 64; o <<= 1) {
        ssum += __shfl_xor(ssum, o);
#pragma unroll
        for (int j = 0; j < 8; ++j) acc[j] += __shfl_xor(acc[j], o);
    }

    // epilogue: channels spread over all 64 lanes (HC/64 per lane)
    float inv = 1.f / (ssum + 1e-16f);
    if constexpr (HC == 128) {
        int ch = 8 * clane + 2 * q;
        float a0s = (q == 0) ? acc[0] : (q == 1) ? acc[2] : (q == 2) ? acc[4] : acc[6];
        float a1s = (q == 0) ? acc[1] : (q == 1) ? acc[3] : (q == 2) ? acc[5] : acc[7];
        float r0v, r1v;
        if (RBF16) {
            uint u = *(const uint*)((const ushort*)resv + (size_t)n * rstride + roff + ch);
            r0v = bflo(u); r1v = bfhi(u);
        } else {
            float2 rr = *(const float2*)((const float*)resv + (size_t)n * rstride + roff + ch);
            r0v = rr.x; r1v = rr.y;
        }
        float2 b2 = *(const float2*)(bias + ch);
        float y0 = fmaf(a0s, inv, b2.x + r0v);
        float y1 = fmaf(a1s, inv, b2.y + r1v);
        float o0 = 0.5f * y0 * (1.f + erff(y0 * 0.70710678118654752f));
        float o1 = 0.5f * y1 * (1.f + erff(y1 * 0.70710678118654752f));
        if (hout) *(float2*)(hout + (size_t)n * hstride + ch) = make_float2(o0, o1);
        if (houtb) *(uint*)(houtb + (size_t)n * HC + ch) = (uint)f2bf(o0) | ((uint)f2bf(o1) << 16);
    } else {
        int ch = 8 * clane + q;
        float a0s = (q == 0) ? acc[0] : (q == 1) ? acc[1] : (q == 2) ? acc[2] : (q == 3) ? acc[3]
                  : (q == 4) ? acc[4] : (q == 5) ? acc[5] : (q == 6) ? acc[6] : acc[7];
        float r0v;
        if (RBF16) r0v = bf2f(((const ushort*)resv)[(size_t)n * rstride + roff + ch]);
        else       r0v = ((const float*)resv)[(size_t)n * rstride + roff + ch];
        float y0 = fmaf(a0s, inv, bias[ch] + r0v);
        float o0 = 0.5f * y0 * (1.f + erff(y0 * 0.70710678118654752f));
        if (hout) hout[(size_t)n * hstride + ch] = o0;
        if (houtb) houtb[(size_t)n * HC + ch] = f2bf(o0);
    }
}

// ---------------- final linear 64 -> 32 ----------------
__global__ __launch_bounds__(256) void final_linear(const float* __restrict__ h,
                                                    const float* __restrict__ W,
                                                    const float* __restrict__ b,
                                                    float* __restrict__ out, int M) {
    __shared__ float Ws[64 * 32];
    __shared__ float bs[32];
    __shared__ float hs[8][64];
    int t = threadIdx.x;
    for (int i = t; i < 64 * 32; i += 256) Ws[i] = W[i];
    if (t < 32) bs[t] = b[t];
    int r0 = blockIdx.x * 8;
    for (int i = t; i < 8 * 64; i += 256) {
        int r = i >> 6, c = i & 63;
        hs[r][c] = (r0 + r < M) ? h[(size_t)(r0 + r) * 64 + c] : 0.f;
    }
    __syncthreads();
    int lr = t >> 5;
    int col = t & 31;
    int row = r0 + lr;
    if (row >= M) return;
    float acc = bs[col];
#pragma unroll 8
    for (int k = 0; k < 64; ++k) acc += hs[lr][k] * Ws[k * 32 + col];
    out[(size_t)row * 32 + col] = acc;
}

extern "C" void kernel_launch(void* const* d_in, const int* in_sizes, int n_in,
                              void* d_out, int out_size, void* d_ws, size_t ws_size,
                              hipStream_t stream) {
    const float* x = (const float*)d_in[0];
    const int* ei = (const int*)d_in[1];
    const int E = in_sizes[1] / 2;
    const int* srcp = ei;
    const int* dstp = ei + E;

    const float* Wl[4]  = {(const float*)d_in[2],  (const float*)d_in[8],  (const float*)d_in[14], (const float*)d_in[20]};
    const float* bl[4]  = {(const float*)d_in[3],  (const float*)d_in[9],  (const float*)d_in[15], (const float*)d_in[21]};
    const float* Wr[4]  = {(const float*)d_in[4],  (const float*)d_in[10], (const float*)d_in[16], (const float*)d_in[22]};
    const float* br[4]  = {(const float*)d_in[5],  (const float*)d_in[11], (const float*)d_in[17], (const float*)d_in[23]};
    const float* att[4] = {(const float*)d_in[6],  (const float*)d_in[12], (const float*)d_in[18], (const float*)d_in[24]};
    const float* bia[4] = {(const float*)d_in[7],  (const float*)d_in[13], (const float*)d_in[19], (const float*)d_in[25]};
    const float* proj1W = (const float*)d_in[26];
    const float* proj1b = (const float*)d_in[27];
    const float* proj4W = (const float*)d_in[28];
    const float* proj4b = (const float*)d_in[29];
    const float* linW   = (const float*)d_in[30];
    const float* linb   = (const float*)d_in[31];

    const int M = NNODES;
    // ---- workspace layout ----
    ushort* xcat = (ushort*)d_ws;                         // [M,384] bf16 max
    ushort* xb   = xcat + (size_t)M * 384;                // [M,224] bf16 (x); later hb [M,128]
    ushort* hb   = xb;                                    // alias
    float* h  = (float*)(xb + (size_t)M * 224);           // [M,128] f32
    float* h4 = h + (size_t)M * 128;                      // [M,64] f32
    ushort* wb = (ushort*)(h4 + (size_t)M * 64);
    ushort* WtC1 = wb; wb += 384 * 224;                   // [Wl1|Wr1|proj1] rows
    ushort* WtC2 = wb; wb += 256 * 128;                   // [Wl2|Wr2]
    ushort* WtC3 = wb; wb += 256 * 128;                   // [Wl3|Wr3]
    ushort* WtC4 = wb; wb += 192 * 128;                   // [Wl4|Wr4|proj4]
    float* bc1 = (float*)wb;                              // 384
    float* bc2 = bc1 + 384;                               // 256
    float* bc3 = bc2 + 256;                               // 256
    float* bc4 = bc3 + 256;                               // 192
    int* deg    = (int*)(bc4 + 192);
    int* cursor = deg + M;
    int* rowptr = cursor + M;
    int* csr    = rowptr + (M + 1);
    int* bsum   = csr + E;

    const int NB = (M + 1023) / 1024;

    // ---- CSR build ----
    hipMemsetAsync(deg, 0, 2 * (size_t)M * sizeof(int), stream);
    hist_kernel<<<(E + 255) / 256, 256, 0, stream>>>(dstp, E, deg);
    scan_part<<<NB, 256, 0, stream>>>(deg, bsum, M);
    scan_bsum<<<1, 128, 0, stream>>>(bsum, NB, rowptr, M);
    scan_apply<<<NB, 256, 0, stream>>>(deg, bsum, rowptr, M);
    scatter_kernel<<<(E + 255) / 256, 256, 0, stream>>>(srcp, dstp, E, rowptr, cursor, csr);

    // ---- weight / bias / x conversion ----
    WConvArgs wa;
    wa.d[0] = {Wl[0],  WtC1,             193, 128, 224};
    wa.d[1] = {Wr[0],  WtC1 + 128 * 224, 193, 128, 224};
    wa.d[2] = {proj1W, WtC1 + 256 * 224, 193, 128, 224};
    wa.d[3] = {Wl[1],  WtC2,             128, 128, 128};
    wa.d[4] = {Wr[1],  WtC2 + 128 * 128, 128, 128, 128};
    wa.d[5] = {Wl[2],  WtC3,             128, 128, 128};
    wa.d[6] = {Wr[2],  WtC3 + 128 * 128, 128, 128, 128};
    wa.d[7] = {Wl[3],  WtC4,             128, 64, 128};
    wa.d[8] = {Wr[3],  WtC4 + 64 * 128,  128, 64, 128};
    wa.d[9] = {proj4W, WtC4 + 128 * 128, 128, 64, 128};
    convert_weights<<<dim3(112, 10), 256, 0, stream>>>(wa);
    BCatArgs ba;
    ba.d[0] = {bl[0],  bc1,       128};
    ba.d[1] = {br[0],  bc1 + 128, 128};
    ba.d[2] = {proj1b, bc1 + 256, 128};
    ba.d[3] = {bl[1],  bc2,       128};
    ba.d[4] = {br[1],  bc2 + 128, 128};
    ba.d[5] = {bl[2],  bc3,       128};
    ba.d[6] = {br[2],  bc3 + 128, 128};
    ba.d[7] = {bl[3],  bc4,       64};
    ba.d[8] = {br[3],  bc4 + 64,  64};
    ba.d[9] = {proj4b, bc4 + 128, 64};
    concat_bias<<<10, 256, 0, stream>>>(ba);
    convert_x<<<2048, 256, 0, stream>>>(x, xb, M);

    const int GX = (M + 127) / 128;
    dim3 ag((M + 3) / 4, 1);

    // ---- layer 1: Kp=224, one fused GEMM (384 cols) ----
    gemm_mfma<128><<<dim3(GX, 3), 256, 0, stream>>>(xb, WtC1, bc1, xcat, M, 224, 384);
    gat_agg<128, true><<<ag, 256, 0, stream>>>(xcat, 384, 128, xcat, 384, 256, att[0], bia[0],
                                               rowptr, csr, h, 128, hb, M);
    // ---- layer 2 ----
    gemm_mfma<128><<<dim3(GX, 2), 256, 0, stream>>>(hb, WtC2, bc2, xcat, M, 128, 256);
    gat_agg<128, false><<<ag, 256, 0, stream>>>(xcat, 256, 128, h, 128, 0, att[1], bia[1],
                                                rowptr, csr, h, 128, hb, M);
    // ---- layer 3 ----
    gemm_mfma<128><<<dim3(GX, 2), 256, 0, stream>>>(hb, WtC3, bc3, xcat, M, 128, 256);
    gat_agg<128, false><<<ag, 256, 0, stream>>>(xcat, 256, 128, h, 128, 0, att[2], bia[2],
                                                rowptr, csr, nullptr, 128, hb, M);
    // ---- layer 4: 3x64 cols fused ----
    gemm_mfma<64><<<dim3(GX, 3), 256, 0, stream>>>(hb, WtC4, bc4, xcat, M, 128, 192);
    gat_agg<64, true><<<ag, 256, 0, stream>>>(xcat, 192, 64, xcat, 192, 128, att[3], bia[3],
                                              rowptr, csr, h4, 64, nullptr, M);
    // ---- final linear 64 -> 32 ----
    final_linear<<<(M + 7) / 8, 256, 0, stream>>>(h4, linW, linb, (float*)d_out, M);
}